// Round 1
// 688.574 us; speedup vs baseline: 1.2075x; 1.2075x over previous
//
#include <hip/hip_runtime.h>
#include <hip/hip_bf16.h>

// ---------------------------------------------------------------------------
// 2-relation GNN layer, fp32 in/out.
//   h_tar = elu(feats0@W0+b0)  -> written straight to out plane 4
//   h_mask = elu(mask@W0+b0)   -> staged in out plane 1
//   g1 = elu(feats1@W1+b1)@A0 ; g2 = elu(feats2@W2+b2)@A1   ((S/c)@A == (S@A)/c)
//   CSR build (count/scan/bucket) over 2E edges, then gather-mean per node:
//   avg_r[v] = mean_{e: src_r[e]=v} g_r[dst_r[e]]
//   planes 0..3 = elu(t+avg1), elu(m+avg1), elu(t+avg2), elu(m+avg2)
// R2 post-mortem: 206M fp32 atomics ran at 251 G/s (atomic-op throughput
// wall, 820us). CSR costs 6.4M int atomics + register accumulation instead.
// R3 post-mortem: bucket_kernel wrote 211MB for a 12.8MB nbr array (16x = 64B
// line granularity on random 4B scatter; dest >> 4MB per-XCD L2). Fix: key-
// sliced scatter — 8 slices bound to XCDs via blockIdx&7; each slice's 1.6MB
// dest range is L2-resident so lines fill before eviction. Edge re-reads are
// L3-absorbed (25.6MB total).
// ---------------------------------------------------------------------------

typedef short  bf16x8 __attribute__((ext_vector_type(8)));
typedef float  f32x4  __attribute__((ext_vector_type(4)));

#define MFMA_BF16(a, b, c) __builtin_amdgcn_mfma_f32_16x16x32_bf16((a), (b), (c), 0, 0, 0)

__device__ __forceinline__ ushort f2bf(float f) {
  return (ushort)((__float_as_uint(f) + 0x8000u) >> 16);  // round-half-up, finite inputs
}
__device__ __forceinline__ float eluf(float x) {
  return x > 0.f ? x : (__expf(x) - 1.f);
}
// pack 8 consecutive fp32 -> bf16x8 (two aligned f32x4 loads)
__device__ __forceinline__ bf16x8 cvt8(const float* __restrict__ p) {
  f32x4 lo = *(const f32x4*)p;
  f32x4 hi = *(const f32x4*)(p + 4);
  union { unsigned u[4]; bf16x8 v; } r;
#pragma unroll
  for (int j = 0; j < 2; ++j) {
    unsigned a = __float_as_uint(lo[2 * j])     + 0x8000u;
    unsigned b = __float_as_uint(lo[2 * j + 1]) + 0x8000u;
    r.u[j] = (a >> 16) | (b & 0xFFFF0000u);
    unsigned c = __float_as_uint(hi[2 * j])     + 0x8000u;
    unsigned d = __float_as_uint(hi[2 * j + 1]) + 0x8000u;
    r.u[2 + j] = (c >> 16) | (d & 0xFFFF0000u);
  }
  return r.v;
}

// ---------------------------------------------------------------------------
// Pack fp32 W0/W1/W2 (128x64) and A0/A1 (64x64) into bf16 MFMA B-fragment
// order. Frag (kc,ct), lane l (q=l>>4, c=l&15): elem i = W[(kc*32+q*8+i)*64+ct*16+c]
// Layout: W0 @0 (16 frags*512), W1 @8192, W2 @16384, A0 @24576 (8), A1 @28672 (8)
// ---------------------------------------------------------------------------
__global__ __launch_bounds__(256) void pack_frags_kernel(
    const float* __restrict__ W0, const float* __restrict__ W1,
    const float* __restrict__ W2, const float* __restrict__ A0,
    const float* __restrict__ A1, ushort* __restrict__ out) {
  int gw   = (blockIdx.x * blockDim.x + threadIdx.x) >> 6;
  int lane = threadIdx.x & 63;
  if (gw >= 64) return;
  const float* src; ushort* dst; int f;
  if (gw < 16)      { src = W0; dst = out;         f = gw;      }
  else if (gw < 32) { src = W1; dst = out + 8192;  f = gw - 16; }
  else if (gw < 48) { src = W2; dst = out + 16384; f = gw - 32; }
  else if (gw < 56) { src = A0; dst = out + 24576; f = gw - 48; }
  else              { src = A1; dst = out + 28672; f = gw - 56; }
  int kc = f >> 2, ct = f & 3;
  int q = lane >> 4, c = lane & 15;
  ushort* d = dst + ((size_t)f * 64 + lane) * 8;
#pragma unroll
  for (int i = 0; i < 8; ++i)
    d[i] = f2bf(src[(kc * 32 + q * 8 + i) * 64 + ct * 16 + c]);
}

// ---------------------------------------------------------------------------
// Y = elu(X@W + b) [optionally @A] ; X: [M x 128] fp32, Y: [M x 64] fp32.
// One wave per 16-row tile. A-frag: m=lane&15, k=(lane>>4)*8+i (m89/m120);
// C/D: col=lane&15, row=(lane>>4)*4+reg (m89).
// ---------------------------------------------------------------------------
template <bool HASA>
__global__ __launch_bounds__(256) void lin_elu_kernel(
    const float* __restrict__ X, const ushort* __restrict__ Wp,
    const float* __restrict__ bias, const ushort* __restrict__ Ap,
    float* __restrict__ Y, int Mtiles) {
  __shared__ ushort plds[4][16 * 72];
  int lane  = threadIdx.x & 63;
  int q     = lane >> 4, c = lane & 15;
  int wslot = threadIdx.x >> 6;
  int wid   = blockIdx.x * 4 + wslot;
  int nw    = gridDim.x * 4;

  bf16x8 bw[4][4];
#pragma unroll
  for (int kc = 0; kc < 4; ++kc)
#pragma unroll
    for (int ct = 0; ct < 4; ++ct)
      bw[kc][ct] = *(const bf16x8*)(Wp + (((kc << 2) | ct) * 64 + lane) * 8);

  float bv[4];
#pragma unroll
  for (int ct = 0; ct < 4; ++ct) bv[ct] = bias[ct * 16 + c];

  bf16x8 ba[2][4];
  if (HASA) {
#pragma unroll
    for (int kc = 0; kc < 2; ++kc)
#pragma unroll
      for (int ct = 0; ct < 4; ++ct)
        ba[kc][ct] = *(const bf16x8*)(Ap + (((kc << 2) | ct) * 64 + lane) * 8);
  }

  ushort* myp = plds[wslot];

  for (int t = wid; t < Mtiles; t += nw) {
    const float* xr = X + ((size_t)(t * 16 + c)) * 128 + q * 8;
    bf16x8 a0 = cvt8(xr);
    bf16x8 a1 = cvt8(xr + 32);
    bf16x8 a2 = cvt8(xr + 64);
    bf16x8 a3 = cvt8(xr + 96);

    f32x4 acc[4];
#pragma unroll
    for (int ct = 0; ct < 4; ++ct) {
      f32x4 a = {0.f, 0.f, 0.f, 0.f};
      a = MFMA_BF16(a0, bw[0][ct], a);
      a = MFMA_BF16(a1, bw[1][ct], a);
      a = MFMA_BF16(a2, bw[2][ct], a);
      a = MFMA_BF16(a3, bw[3][ct], a);
      acc[ct] = a;
    }

    float* yr = Y + ((size_t)t * 16) * 64;
    if (!HASA) {
#pragma unroll
      for (int ct = 0; ct < 4; ++ct)
#pragma unroll
        for (int r = 0; r < 4; ++r)
          yr[(q * 4 + r) * 64 + ct * 16 + c] = eluf(acc[ct][r] + bv[ct]);
    } else {
      // stage elu'd tile as bf16 in wave-private LDS, reload as A-fragments
#pragma unroll
      for (int ct = 0; ct < 4; ++ct)
#pragma unroll
        for (int r = 0; r < 4; ++r)
          myp[(q * 4 + r) * 72 + ct * 16 + c] = f2bf(eluf(acc[ct][r] + bv[ct]));
      bf16x8 p0 = *(const bf16x8*)(myp + c * 72 + q * 8);
      bf16x8 p1 = *(const bf16x8*)(myp + c * 72 + 32 + q * 8);
      f32x4 acc2[4];
#pragma unroll
      for (int ct = 0; ct < 4; ++ct) {
        f32x4 a = {0.f, 0.f, 0.f, 0.f};
        a = MFMA_BF16(p0, ba[0][ct], a);
        a = MFMA_BF16(p1, ba[1][ct], a);
        acc2[ct] = a;
      }
#pragma unroll
      for (int ct = 0; ct < 4; ++ct)
#pragma unroll
        for (int r = 0; r < 4; ++r)
          yr[(q * 4 + r) * 64 + ct * 16 + c] = acc2[ct][r];
    }
  }
}

// ---------------------------------------------------------------------------
// CSR build. Key space: [0, 2N): relation1 nodes 0..N-1, relation2 N..2N-1.
// ---------------------------------------------------------------------------
__global__ __launch_bounds__(256) void count_kernel(
    const int* __restrict__ src1, const int* __restrict__ src2,
    int* __restrict__ cnt, int E, int N) {
  int e = blockIdx.x * blockDim.x + threadIdx.x;
  if (e < E)           atomicAdd(&cnt[src1[e]], 1);
  else if (e < 2 * E)  atomicAdd(&cnt[N + src2[e - E]], 1);
}

// scan stage 1: per-block (2048 elems) sums
__global__ __launch_bounds__(256) void scan_sums_kernel(
    const int* __restrict__ cnt, int* __restrict__ partial, int n) {
  __shared__ int lds[256];
  int t = threadIdx.x, base = blockIdx.x * 2048 + t * 8;
  int s = 0;
#pragma unroll
  for (int j = 0; j < 8; ++j) { int i = base + j; s += (i < n) ? cnt[i] : 0; }
  lds[t] = s; __syncthreads();
  for (int off = 128; off > 0; off >>= 1) {
    if (t < off) lds[t] += lds[t + off];
    __syncthreads();
  }
  if (t == 0) partial[blockIdx.x] = lds[0];
}

// scan stage 2: single-block exclusive scan of partials (nb <= 256);
// thread nb-1 also writes row_ptr[n] = grand total.
__global__ __launch_bounds__(256) void scan_partials_kernel(
    int* __restrict__ partial, int* __restrict__ row_ptr, int nb, int n) {
  __shared__ int lds[256];
  int t = threadIdx.x;
  int v = (t < nb) ? partial[t] : 0;
  lds[t] = v; __syncthreads();
  for (int off = 1; off < 256; off <<= 1) {
    int x = lds[t];
    int a = (t >= off) ? lds[t - off] : 0;
    __syncthreads();
    lds[t] = x + a;
    __syncthreads();
  }
  int incl = lds[t];
  if (t < nb) partial[t] = incl - v;          // exclusive
  if (t == nb - 1) row_ptr[n] = incl;          // total = 2E
}

// scan stage 3: recompute local sums, block-exclusive-scan thread sums,
// write row_ptr and cursor (bucket cursors start at row begin).
__global__ __launch_bounds__(256) void scan_write_kernel(
    const int* __restrict__ cnt, const int* __restrict__ partial,
    int* __restrict__ row_ptr, int* __restrict__ cursor, int n) {
  __shared__ int lds[256];
  int t = threadIdx.x, base = blockIdx.x * 2048 + t * 8;
  int c[8]; int s = 0;
#pragma unroll
  for (int j = 0; j < 8; ++j) { int i = base + j; c[j] = (i < n) ? cnt[i] : 0; s += c[j]; }
  lds[t] = s; __syncthreads();
  for (int off = 1; off < 256; off <<= 1) {
    int x = lds[t];
    int a = (t >= off) ? lds[t - off] : 0;
    __syncthreads();
    lds[t] = x + a;
    __syncthreads();
  }
  int run = partial[blockIdx.x] + lds[t] - s;  // exclusive prefix for this thread
#pragma unroll
  for (int j = 0; j < 8; ++j) {
    int i = base + j;
    if (i < n) { row_ptr[i] = run; cursor[i] = run; }
    run += c[j];
  }
}

// ---------------------------------------------------------------------------
// Key-sliced bucket scatter. 8 key slices, slice = blockIdx&7 (XCD round-robin)
// so each slice's ~1.6MB nbr range + ~100KB cursor slice stay in ONE XCD's L2;
// 64B lines fill completely before eviction (kills the 16x write amp).
// Each slice re-scans one relation's edge list (6.4MB, L3-resident after the
// first slice touches it); dst is only loaded on filter hit (~1/4).
// ---------------------------------------------------------------------------
__global__ __launch_bounds__(256) void bucket_kernel(
    const int* __restrict__ src1, const int* __restrict__ dst1,
    const int* __restrict__ src2, const int* __restrict__ dst2,
    int* __restrict__ cursor, int* __restrict__ nbr, int E, int N) {
  int M     = 2 * N;
  int per   = (M + 7) >> 3;
  int slice = blockIdx.x & 7;
  int blk   = blockIdx.x >> 3;
  int nth   = (gridDim.x >> 3) * blockDim.x;
  int tid   = blk * blockDim.x + threadIdx.x;
  int klo   = slice * per;
  int khi   = klo + per; if (khi > M) khi = M;
  int n4    = E >> 2;

  // relation 1: keys in [0, N)
  if (klo < N) {
    int lo = klo, hi = khi < N ? khi : N;
    const int4* s4 = (const int4*)src1;
    for (int i = tid; i < n4; i += nth) {
      int4 k = s4[i];
      int e = i << 2;
      if (k.x >= lo && k.x < hi) { int p = atomicAdd(&cursor[k.x], 1); nbr[p] = dst1[e];     }
      if (k.y >= lo && k.y < hi) { int p = atomicAdd(&cursor[k.y], 1); nbr[p] = dst1[e + 1]; }
      if (k.z >= lo && k.z < hi) { int p = atomicAdd(&cursor[k.z], 1); nbr[p] = dst1[e + 2]; }
      if (k.w >= lo && k.w < hi) { int p = atomicAdd(&cursor[k.w], 1); nbr[p] = dst1[e + 3]; }
    }
    for (int e = (n4 << 2) + tid; e < E; e += nth) {
      int k = src1[e];
      if (k >= lo && k < hi) { int p = atomicAdd(&cursor[k], 1); nbr[p] = dst1[e]; }
    }
  }
  // relation 2: keys in [N, 2N)
  if (khi > N) {
    int lo = (klo > N ? klo : N) - N, hi = khi - N;
    const int4* s4 = (const int4*)src2;
    for (int i = tid; i < n4; i += nth) {
      int4 k = s4[i];
      int e = i << 2;
      if (k.x >= lo && k.x < hi) { int p = atomicAdd(&cursor[N + k.x], 1); nbr[p] = dst2[e];     }
      if (k.y >= lo && k.y < hi) { int p = atomicAdd(&cursor[N + k.y], 1); nbr[p] = dst2[e + 1]; }
      if (k.z >= lo && k.z < hi) { int p = atomicAdd(&cursor[N + k.z], 1); nbr[p] = dst2[e + 2]; }
      if (k.w >= lo && k.w < hi) { int p = atomicAdd(&cursor[N + k.w], 1); nbr[p] = dst2[e + 3]; }
    }
    for (int e = (n4 << 2) + tid; e < E; e += nth) {
      int k = src2[e];
      if (k >= lo && k < hi) { int p = atomicAdd(&cursor[N + k], 1); nbr[p] = dst2[e]; }
    }
  }
}

// ---------------------------------------------------------------------------
// Gather-mean: one wave per key v in [0,2N). Lane j owns column j; each
// neighbor row is a 256B coalesced read from g (g1+g2 = 23MB, L2/L3-resident).
// avg = sum/deg (deg==0 -> 0), written dense -> finalize needs no counts.
// ---------------------------------------------------------------------------
__global__ __launch_bounds__(256) void aggregate_kernel(
    const int* __restrict__ row_ptr, const int* __restrict__ nbr,
    const float* __restrict__ g1, const float* __restrict__ g2,
    float* __restrict__ avg1, float* __restrict__ avg2, int N) {
  int lane = threadIdx.x & 63;
  int v = blockIdx.x * 4 + (threadIdx.x >> 6);
  if (v >= 2 * N) return;
  int n0 = row_ptr[v], n1 = row_ptr[v + 1];
  const float* __restrict__ g = (v < N) ? g1 : g2;
  float acc = 0.f;
  for (int base = n0; base < n1; base += 64) {
    int rem = n1 - base;
    int m = rem < 64 ? rem : 64;
    int idx = (lane < m) ? nbr[base + lane] : 0;
    int j = 0;
    for (; j + 4 <= m; j += 4) {  // 4 independent gathers in flight
      int d0 = __shfl(idx, j), d1 = __shfl(idx, j + 1);
      int d2 = __shfl(idx, j + 2), d3 = __shfl(idx, j + 3);
      float v0 = g[(size_t)d0 * 64 + lane];
      float v1 = g[(size_t)d1 * 64 + lane];
      float v2 = g[(size_t)d2 * 64 + lane];
      float v3 = g[(size_t)d3 * 64 + lane];
      acc += v0 + v1 + v2 + v3;
    }
    for (; j < m; ++j) {
      int d = __shfl(idx, j);
      acc += g[(size_t)d * 64 + lane];
    }
  }
  int deg = n1 - n0;
  float a = (deg > 0) ? acc / (float)deg : 0.f;
  if (v < N) avg1[(size_t)v * 64 + lane] = a;
  else       avg2[(size_t)(v - N) * 64 + lane] = a;
}

// ---------------------------------------------------------------------------
// Finalize: one thread per float4. t from out plane 4, m staged in plane 1.
// ---------------------------------------------------------------------------
__global__ __launch_bounds__(256) void finalize_kernel(
    const float* __restrict__ avg1, const float* __restrict__ avg2,
    float* __restrict__ out, int N) {
  int i = blockIdx.x * blockDim.x + threadIdx.x;
  if (i >= N * 16) return;
  size_t base  = ((size_t)i) << 2;
  size_t plane = (size_t)N * 64;
  f32x4 t = *(const f32x4*)(out + 4 * plane + base);
  f32x4 m = *(const f32x4*)(out + plane + base);
  f32x4 a1 = *(const f32x4*)(avg1 + base);
  f32x4 a2 = *(const f32x4*)(avg2 + base);
  f32x4 v1, m1, v2, m2;
#pragma unroll
  for (int j = 0; j < 4; ++j) {
    v1[j] = eluf(t[j] + a1[j]);
    m1[j] = eluf(m[j] + a1[j]);
    v2[j] = eluf(t[j] + a2[j]);
    m2[j] = eluf(m[j] + a2[j]);
  }
  *(f32x4*)(out + base)             = v1;
  *(f32x4*)(out + plane + base)     = m1;
  *(f32x4*)(out + 2 * plane + base) = v2;
  *(f32x4*)(out + 3 * plane + base) = m2;
}

static inline int imin(int a, int b) { return a < b ? a : b; }

extern "C" void kernel_launch(void* const* d_in, const int* in_sizes, int n_in,
                              void* d_out, int out_size, void* d_ws, size_t ws_size,
                              hipStream_t stream) {
  const float* feats0 = (const float*)d_in[0];
  const float* feats1 = (const float*)d_in[1];
  const float* feats2 = (const float*)d_in[2];
  const float* maskf  = (const float*)d_in[3];
  const int* src1 = (const int*)d_in[4];
  const int* dst1 = (const int*)d_in[5];
  const int* src2 = (const int*)d_in[6];
  const int* dst2 = (const int*)d_in[7];
  const float* W0 = (const float*)d_in[8];
  const float* b0 = (const float*)d_in[9];
  const float* W1 = (const float*)d_in[10];
  const float* b1 = (const float*)d_in[11];
  const float* W2 = (const float*)d_in[12];
  const float* b2 = (const float*)d_in[13];
  const float* A0 = (const float*)d_in[14];
  const float* A1 = (const float*)d_in[15];

  int N  = in_sizes[0] / 128;
  int N1 = in_sizes[1] / 128;
  int N2 = in_sizes[2] / 128;
  int E  = in_sizes[4];
  int M  = 2 * N;                    // CSR key space (both relations)

  float* out = (float*)d_out;
  size_t plane = (size_t)N * 64;
  float* h_tar  = out + 4 * plane;   // final value of plane 4 IS h_tar
  float* h_mask = out + plane;       // staged; finalize overwrites with mask1

  // Workspace (~90 MB; R0 validated ws_size >= ~126 MB)
  float* g1      = (float*)d_ws;               // N1*64
  float* g2      = g1 + (size_t)N1 * 64;       // N2*64
  float* avg1    = g2 + (size_t)N2 * 64;       // N*64
  float* avg2    = avg1 + (size_t)N * 64;      // N*64
  int*   cnt     = (int*)(avg2 + (size_t)N * 64);  // M
  int*   row_ptr = cnt + M;                    // M+1
  int*   cursor  = row_ptr + M + 1;            // M
  int*   partial = cursor + M;                 // <=256
  int*   nbr     = partial + 256;              // 2E
  ushort* frags  = (ushort*)(nbr + 2 * E);     // 32768 ushorts (64 KB)

  hipMemsetAsync(cnt, 0, (size_t)M * sizeof(int), stream);

  pack_frags_kernel<<<16, 256, 0, stream>>>(W0, W1, W2, A0, A1, frags);

  int t0 = N / 16, t1 = N1 / 16, t2 = N2 / 16;
  lin_elu_kernel<false><<<imin(2048, (t0 + 3) / 4), 256, 0, stream>>>(
      feats0, frags, b0, nullptr, h_tar, t0);
  lin_elu_kernel<false><<<imin(2048, (t0 + 3) / 4), 256, 0, stream>>>(
      maskf, frags, b0, nullptr, h_mask, t0);
  lin_elu_kernel<true><<<imin(2048, (t1 + 3) / 4), 256, 0, stream>>>(
      feats1, frags + 8192, b1, frags + 24576, g1, t1);
  lin_elu_kernel<true><<<imin(2048, (t2 + 3) / 4), 256, 0, stream>>>(
      feats2, frags + 16384, b2, frags + 28672, g2, t2);

  // CSR build
  count_kernel<<<(2 * E + 255) / 256, 256, 0, stream>>>(src1, src2, cnt, E, N);
  int nb = (M + 2047) / 2048;  // 98 for N=100000; fits single-block stage 2
  scan_sums_kernel<<<nb, 256, 0, stream>>>(cnt, partial, M);
  scan_partials_kernel<<<1, 256, 0, stream>>>(partial, row_ptr, nb, M);
  scan_write_kernel<<<nb, 256, 0, stream>>>(cnt, partial, row_ptr, cursor, M);
  // 8 key slices x 128 blocks each; slice = blockIdx&7 rides XCD round-robin
  bucket_kernel<<<1024, 256, 0, stream>>>(
      src1, dst1, src2, dst2, cursor, nbr, E, N);

  // Gather-mean
  aggregate_kernel<<<(M + 3) / 4, 256, 0, stream>>>(
      row_ptr, nbr, g1, g2, avg1, avg2, N);

  finalize_kernel<<<(N * 16 + 255) / 256, 256, 0, stream>>>(avg1, avg2, out, N);
}

// Round 2
// 684.032 us; speedup vs baseline: 1.2155x; 1.0066x over previous
//
#include <hip/hip_runtime.h>
#include <hip/hip_bf16.h>

// ---------------------------------------------------------------------------
// 2-relation GNN layer, fp32 in/out.
//   h_tar = elu(feats0@W0+b0)  -> written straight to out plane 4
//   h_mask = elu(mask@W0+b0)   -> staged in out plane 1
//   g1 = elu(feats1@W1+b1)@A0 ; g2 = elu(feats2@W2+b2)@A1   ((S/c)@A == (S@A)/c)
//   CSR build (count/scan/bucket) over 2E edges, then gather-mean per node:
//   avg_r[v] = mean_{e: src_r[e]=v} g_r[dst_r[e]]
//   planes 0..3 = elu(t+avg1), elu(m+avg1), elu(t+avg2), elu(m+avg2)
// R2 post-mortem: 206M fp32 atomics ran at 251 G/s (atomic-op throughput
// wall, 820us). CSR costs 6.4M int atomics + register accumulation instead.
// R3 post-mortem: bucket_kernel wrote 211MB for a 12.8MB nbr array (16x = 64B
// line granularity on random 4B scatter; dest >> 4MB per-XCD L2). Fix: key-
// sliced scatter — 8 slices bound to XCDs via blockIdx&7.
// R4 post-mortem: slicing fixed reads (FETCH 50MB, L3-absorbed) but WRITE
// stayed 208MB — the slice's own 12.8MB streaming edge reads thrash the L2
// and evict partially-filled dest lines. Fix: non-temporal (nt) loads on all
// edge streams so L2 keeps only the 1.6MB dest + 100KB cursor resident.
// ---------------------------------------------------------------------------

typedef short  bf16x8 __attribute__((ext_vector_type(8)));
typedef float  f32x4  __attribute__((ext_vector_type(4)));
typedef int    i32x4  __attribute__((ext_vector_type(4)));

#define MFMA_BF16(a, b, c) __builtin_amdgcn_mfma_f32_16x16x32_bf16((a), (b), (c), 0, 0, 0)

__device__ __forceinline__ ushort f2bf(float f) {
  return (ushort)((__float_as_uint(f) + 0x8000u) >> 16);  // round-half-up, finite inputs
}
__device__ __forceinline__ float eluf(float x) {
  return x > 0.f ? x : (__expf(x) - 1.f);
}
// pack 8 consecutive fp32 -> bf16x8 (two aligned f32x4 loads)
__device__ __forceinline__ bf16x8 cvt8(const float* __restrict__ p) {
  f32x4 lo = *(const f32x4*)p;
  f32x4 hi = *(const f32x4*)(p + 4);
  union { unsigned u[4]; bf16x8 v; } r;
#pragma unroll
  for (int j = 0; j < 2; ++j) {
    unsigned a = __float_as_uint(lo[2 * j])     + 0x8000u;
    unsigned b = __float_as_uint(lo[2 * j + 1]) + 0x8000u;
    r.u[j] = (a >> 16) | (b & 0xFFFF0000u);
    unsigned c = __float_as_uint(hi[2 * j])     + 0x8000u;
    unsigned d = __float_as_uint(hi[2 * j + 1]) + 0x8000u;
    r.u[2 + j] = (c >> 16) | (d & 0xFFFF0000u);
  }
  return r.v;
}

// ---------------------------------------------------------------------------
// Pack fp32 W0/W1/W2 (128x64) and A0/A1 (64x64) into bf16 MFMA B-fragment
// order. Frag (kc,ct), lane l (q=l>>4, c=l&15): elem i = W[(kc*32+q*8+i)*64+ct*16+c]
// Layout: W0 @0 (16 frags*512), W1 @8192, W2 @16384, A0 @24576 (8), A1 @28672 (8)
// ---------------------------------------------------------------------------
__global__ __launch_bounds__(256) void pack_frags_kernel(
    const float* __restrict__ W0, const float* __restrict__ W1,
    const float* __restrict__ W2, const float* __restrict__ A0,
    const float* __restrict__ A1, ushort* __restrict__ out) {
  int gw   = (blockIdx.x * blockDim.x + threadIdx.x) >> 6;
  int lane = threadIdx.x & 63;
  if (gw >= 64) return;
  const float* src; ushort* dst; int f;
  if (gw < 16)      { src = W0; dst = out;         f = gw;      }
  else if (gw < 32) { src = W1; dst = out + 8192;  f = gw - 16; }
  else if (gw < 48) { src = W2; dst = out + 16384; f = gw - 32; }
  else if (gw < 56) { src = A0; dst = out + 24576; f = gw - 48; }
  else              { src = A1; dst = out + 28672; f = gw - 56; }
  int kc = f >> 2, ct = f & 3;
  int q = lane >> 4, c = lane & 15;
  ushort* d = dst + ((size_t)f * 64 + lane) * 8;
#pragma unroll
  for (int i = 0; i < 8; ++i)
    d[i] = f2bf(src[(kc * 32 + q * 8 + i) * 64 + ct * 16 + c]);
}

// ---------------------------------------------------------------------------
// Y = elu(X@W + b) [optionally @A] ; X: [M x 128] fp32, Y: [M x 64] fp32.
// One wave per 16-row tile. A-frag: m=lane&15, k=(lane>>4)*8+i (m89/m120);
// C/D: col=lane&15, row=(lane>>4)*4+reg (m89).
// ---------------------------------------------------------------------------
template <bool HASA>
__global__ __launch_bounds__(256) void lin_elu_kernel(
    const float* __restrict__ X, const ushort* __restrict__ Wp,
    const float* __restrict__ bias, const ushort* __restrict__ Ap,
    float* __restrict__ Y, int Mtiles) {
  __shared__ ushort plds[4][16 * 72];
  int lane  = threadIdx.x & 63;
  int q     = lane >> 4, c = lane & 15;
  int wslot = threadIdx.x >> 6;
  int wid   = blockIdx.x * 4 + wslot;
  int nw    = gridDim.x * 4;

  bf16x8 bw[4][4];
#pragma unroll
  for (int kc = 0; kc < 4; ++kc)
#pragma unroll
    for (int ct = 0; ct < 4; ++ct)
      bw[kc][ct] = *(const bf16x8*)(Wp + (((kc << 2) | ct) * 64 + lane) * 8);

  float bv[4];
#pragma unroll
  for (int ct = 0; ct < 4; ++ct) bv[ct] = bias[ct * 16 + c];

  bf16x8 ba[2][4];
  if (HASA) {
#pragma unroll
    for (int kc = 0; kc < 2; ++kc)
#pragma unroll
      for (int ct = 0; ct < 4; ++ct)
        ba[kc][ct] = *(const bf16x8*)(Ap + (((kc << 2) | ct) * 64 + lane) * 8);
  }

  ushort* myp = plds[wslot];

  for (int t = wid; t < Mtiles; t += nw) {
    const float* xr = X + ((size_t)(t * 16 + c)) * 128 + q * 8;
    bf16x8 a0 = cvt8(xr);
    bf16x8 a1 = cvt8(xr + 32);
    bf16x8 a2 = cvt8(xr + 64);
    bf16x8 a3 = cvt8(xr + 96);

    f32x4 acc[4];
#pragma unroll
    for (int ct = 0; ct < 4; ++ct) {
      f32x4 a = {0.f, 0.f, 0.f, 0.f};
      a = MFMA_BF16(a0, bw[0][ct], a);
      a = MFMA_BF16(a1, bw[1][ct], a);
      a = MFMA_BF16(a2, bw[2][ct], a);
      a = MFMA_BF16(a3, bw[3][ct], a);
      acc[ct] = a;
    }

    float* yr = Y + ((size_t)t * 16) * 64;
    if (!HASA) {
#pragma unroll
      for (int ct = 0; ct < 4; ++ct)
#pragma unroll
        for (int r = 0; r < 4; ++r)
          yr[(q * 4 + r) * 64 + ct * 16 + c] = eluf(acc[ct][r] + bv[ct]);
    } else {
      // stage elu'd tile as bf16 in wave-private LDS, reload as A-fragments
#pragma unroll
      for (int ct = 0; ct < 4; ++ct)
#pragma unroll
        for (int r = 0; r < 4; ++r)
          myp[(q * 4 + r) * 72 + ct * 16 + c] = f2bf(eluf(acc[ct][r] + bv[ct]));
      bf16x8 p0 = *(const bf16x8*)(myp + c * 72 + q * 8);
      bf16x8 p1 = *(const bf16x8*)(myp + c * 72 + 32 + q * 8);
      f32x4 acc2[4];
#pragma unroll
      for (int ct = 0; ct < 4; ++ct) {
        f32x4 a = {0.f, 0.f, 0.f, 0.f};
        a = MFMA_BF16(p0, ba[0][ct], a);
        a = MFMA_BF16(p1, ba[1][ct], a);
        acc2[ct] = a;
      }
#pragma unroll
      for (int ct = 0; ct < 4; ++ct)
#pragma unroll
        for (int r = 0; r < 4; ++r)
          yr[(q * 4 + r) * 64 + ct * 16 + c] = acc2[ct][r];
    }
  }
}

// ---------------------------------------------------------------------------
// CSR build. Key space: [0, 2N): relation1 nodes 0..N-1, relation2 N..2N-1.
// nt loads: keep the streaming edge reads from evicting cnt's atomic lines.
// ---------------------------------------------------------------------------
__global__ __launch_bounds__(256) void count_kernel(
    const int* __restrict__ src1, const int* __restrict__ src2,
    int* __restrict__ cnt, int E, int N) {
  int e = blockIdx.x * blockDim.x + threadIdx.x;
  if (e < E)           atomicAdd(&cnt[__builtin_nontemporal_load(src1 + e)], 1);
  else if (e < 2 * E)  atomicAdd(&cnt[N + __builtin_nontemporal_load(src2 + e - E)], 1);
}

// scan stage 1: per-block (2048 elems) sums
__global__ __launch_bounds__(256) void scan_sums_kernel(
    const int* __restrict__ cnt, int* __restrict__ partial, int n) {
  __shared__ int lds[256];
  int t = threadIdx.x, base = blockIdx.x * 2048 + t * 8;
  int s = 0;
#pragma unroll
  for (int j = 0; j < 8; ++j) { int i = base + j; s += (i < n) ? cnt[i] : 0; }
  lds[t] = s; __syncthreads();
  for (int off = 128; off > 0; off >>= 1) {
    if (t < off) lds[t] += lds[t + off];
    __syncthreads();
  }
  if (t == 0) partial[blockIdx.x] = lds[0];
}

// scan stage 2: single-block exclusive scan of partials (nb <= 256);
// thread nb-1 also writes row_ptr[n] = grand total.
__global__ __launch_bounds__(256) void scan_partials_kernel(
    int* __restrict__ partial, int* __restrict__ row_ptr, int nb, int n) {
  __shared__ int lds[256];
  int t = threadIdx.x;
  int v = (t < nb) ? partial[t] : 0;
  lds[t] = v; __syncthreads();
  for (int off = 1; off < 256; off <<= 1) {
    int x = lds[t];
    int a = (t >= off) ? lds[t - off] : 0;
    __syncthreads();
    lds[t] = x + a;
    __syncthreads();
  }
  int incl = lds[t];
  if (t < nb) partial[t] = incl - v;          // exclusive
  if (t == nb - 1) row_ptr[n] = incl;          // total = 2E
}

// scan stage 3: recompute local sums, block-exclusive-scan thread sums,
// write row_ptr and cursor (bucket cursors start at row begin).
__global__ __launch_bounds__(256) void scan_write_kernel(
    const int* __restrict__ cnt, const int* __restrict__ partial,
    int* __restrict__ row_ptr, int* __restrict__ cursor, int n) {
  __shared__ int lds[256];
  int t = threadIdx.x, base = blockIdx.x * 2048 + t * 8;
  int c[8]; int s = 0;
#pragma unroll
  for (int j = 0; j < 8; ++j) { int i = base + j; c[j] = (i < n) ? cnt[i] : 0; s += c[j]; }
  lds[t] = s; __syncthreads();
  for (int off = 1; off < 256; off <<= 1) {
    int x = lds[t];
    int a = (t >= off) ? lds[t - off] : 0;
    __syncthreads();
    lds[t] = x + a;
    __syncthreads();
  }
  int run = partial[blockIdx.x] + lds[t] - s;  // exclusive prefix for this thread
#pragma unroll
  for (int j = 0; j < 8; ++j) {
    int i = base + j;
    if (i < n) { row_ptr[i] = run; cursor[i] = run; }
    run += c[j];
  }
}

// ---------------------------------------------------------------------------
// Key-sliced bucket scatter. 8 key slices, slice = blockIdx&7 (XCD round-robin)
// so each slice's ~1.6MB nbr range + ~100KB cursor slice stay in ONE XCD's L2.
// All streaming edge reads are NON-TEMPORAL (evict-first in L2) so they can't
// evict partially-filled dest lines: each 64B nbr line collects its 16 stores
// in L2 and is written back ONCE. Edge re-reads (4x per relation) are
// L3-absorbed. dst is only loaded on filter hit (~1/4).
// ---------------------------------------------------------------------------
__global__ __launch_bounds__(256) void bucket_kernel(
    const int* __restrict__ src1, const int* __restrict__ dst1,
    const int* __restrict__ src2, const int* __restrict__ dst2,
    int* __restrict__ cursor, int* __restrict__ nbr, int E, int N) {
  int M     = 2 * N;
  int per   = (M + 7) >> 3;
  int slice = blockIdx.x & 7;
  int blk   = blockIdx.x >> 3;
  int nth   = (gridDim.x >> 3) * blockDim.x;
  int tid   = blk * blockDim.x + threadIdx.x;
  int klo   = slice * per;
  int khi   = klo + per; if (khi > M) khi = M;
  int n4    = E >> 2;

  // relation 1: keys in [0, N)
  if (klo < N) {
    int lo = klo, hi = khi < N ? khi : N;
    const i32x4* s4 = (const i32x4*)src1;
    for (int i = tid; i < n4; i += nth) {
      i32x4 k = __builtin_nontemporal_load(s4 + i);
      int e = i << 2;
      if (k[0] >= lo && k[0] < hi) { int p = atomicAdd(&cursor[k[0]], 1); nbr[p] = __builtin_nontemporal_load(dst1 + e);     }
      if (k[1] >= lo && k[1] < hi) { int p = atomicAdd(&cursor[k[1]], 1); nbr[p] = __builtin_nontemporal_load(dst1 + e + 1); }
      if (k[2] >= lo && k[2] < hi) { int p = atomicAdd(&cursor[k[2]], 1); nbr[p] = __builtin_nontemporal_load(dst1 + e + 2); }
      if (k[3] >= lo && k[3] < hi) { int p = atomicAdd(&cursor[k[3]], 1); nbr[p] = __builtin_nontemporal_load(dst1 + e + 3); }
    }
    for (int e = (n4 << 2) + tid; e < E; e += nth) {
      int k = __builtin_nontemporal_load(src1 + e);
      if (k >= lo && k < hi) { int p = atomicAdd(&cursor[k], 1); nbr[p] = __builtin_nontemporal_load(dst1 + e); }
    }
  }
  // relation 2: keys in [N, 2N)
  if (khi > N) {
    int lo = (klo > N ? klo : N) - N, hi = khi - N;
    const i32x4* s4 = (const i32x4*)src2;
    for (int i = tid; i < n4; i += nth) {
      i32x4 k = __builtin_nontemporal_load(s4 + i);
      int e = i << 2;
      if (k[0] >= lo && k[0] < hi) { int p = atomicAdd(&cursor[N + k[0]], 1); nbr[p] = __builtin_nontemporal_load(dst2 + e);     }
      if (k[1] >= lo && k[1] < hi) { int p = atomicAdd(&cursor[N + k[1]], 1); nbr[p] = __builtin_nontemporal_load(dst2 + e + 1); }
      if (k[2] >= lo && k[2] < hi) { int p = atomicAdd(&cursor[N + k[2]], 1); nbr[p] = __builtin_nontemporal_load(dst2 + e + 2); }
      if (k[3] >= lo && k[3] < hi) { int p = atomicAdd(&cursor[N + k[3]], 1); nbr[p] = __builtin_nontemporal_load(dst2 + e + 3); }
    }
    for (int e = (n4 << 2) + tid; e < E; e += nth) {
      int k = __builtin_nontemporal_load(src2 + e);
      if (k >= lo && k < hi) { int p = atomicAdd(&cursor[N + k], 1); nbr[p] = __builtin_nontemporal_load(dst2 + e); }
    }
  }
}

// ---------------------------------------------------------------------------
// Gather-mean: one wave per key v in [0,2N). Lane j owns column j; each
// neighbor row is a 256B coalesced read from g (g1+g2 = 23MB, L2/L3-resident).
// avg = sum/deg (deg==0 -> 0), written dense -> finalize needs no counts.
// ---------------------------------------------------------------------------
__global__ __launch_bounds__(256) void aggregate_kernel(
    const int* __restrict__ row_ptr, const int* __restrict__ nbr,
    const float* __restrict__ g1, const float* __restrict__ g2,
    float* __restrict__ avg1, float* __restrict__ avg2, int N) {
  int lane = threadIdx.x & 63;
  int v = blockIdx.x * 4 + (threadIdx.x >> 6);
  if (v >= 2 * N) return;
  int n0 = row_ptr[v], n1 = row_ptr[v + 1];
  const float* __restrict__ g = (v < N) ? g1 : g2;
  float acc = 0.f;
  for (int base = n0; base < n1; base += 64) {
    int rem = n1 - base;
    int m = rem < 64 ? rem : 64;
    int idx = (lane < m) ? nbr[base + lane] : 0;
    int j = 0;
    for (; j + 4 <= m; j += 4) {  // 4 independent gathers in flight
      int d0 = __shfl(idx, j), d1 = __shfl(idx, j + 1);
      int d2 = __shfl(idx, j + 2), d3 = __shfl(idx, j + 3);
      float v0 = g[(size_t)d0 * 64 + lane];
      float v1 = g[(size_t)d1 * 64 + lane];
      float v2 = g[(size_t)d2 * 64 + lane];
      float v3 = g[(size_t)d3 * 64 + lane];
      acc += v0 + v1 + v2 + v3;
    }
    for (; j < m; ++j) {
      int d = __shfl(idx, j);
      acc += g[(size_t)d * 64 + lane];
    }
  }
  int deg = n1 - n0;
  float a = (deg > 0) ? acc / (float)deg : 0.f;
  if (v < N) avg1[(size_t)v * 64 + lane] = a;
  else       avg2[(size_t)(v - N) * 64 + lane] = a;
}

// ---------------------------------------------------------------------------
// Finalize: one thread per float4. t from out plane 4, m staged in plane 1.
// ---------------------------------------------------------------------------
__global__ __launch_bounds__(256) void finalize_kernel(
    const float* __restrict__ avg1, const float* __restrict__ avg2,
    float* __restrict__ out, int N) {
  int i = blockIdx.x * blockDim.x + threadIdx.x;
  if (i >= N * 16) return;
  size_t base  = ((size_t)i) << 2;
  size_t plane = (size_t)N * 64;
  f32x4 t = *(const f32x4*)(out + 4 * plane + base);
  f32x4 m = *(const f32x4*)(out + plane + base);
  f32x4 a1 = *(const f32x4*)(avg1 + base);
  f32x4 a2 = *(const f32x4*)(avg2 + base);
  f32x4 v1, m1, v2, m2;
#pragma unroll
  for (int j = 0; j < 4; ++j) {
    v1[j] = eluf(t[j] + a1[j]);
    m1[j] = eluf(m[j] + a1[j]);
    v2[j] = eluf(t[j] + a2[j]);
    m2[j] = eluf(m[j] + a2[j]);
  }
  *(f32x4*)(out + base)             = v1;
  *(f32x4*)(out + plane + base)     = m1;
  *(f32x4*)(out + 2 * plane + base) = v2;
  *(f32x4*)(out + 3 * plane + base) = m2;
}

static inline int imin(int a, int b) { return a < b ? a : b; }

extern "C" void kernel_launch(void* const* d_in, const int* in_sizes, int n_in,
                              void* d_out, int out_size, void* d_ws, size_t ws_size,
                              hipStream_t stream) {
  const float* feats0 = (const float*)d_in[0];
  const float* feats1 = (const float*)d_in[1];
  const float* feats2 = (const float*)d_in[2];
  const float* maskf  = (const float*)d_in[3];
  const int* src1 = (const int*)d_in[4];
  const int* dst1 = (const int*)d_in[5];
  const int* src2 = (const int*)d_in[6];
  const int* dst2 = (const int*)d_in[7];
  const float* W0 = (const float*)d_in[8];
  const float* b0 = (const float*)d_in[9];
  const float* W1 = (const float*)d_in[10];
  const float* b1 = (const float*)d_in[11];
  const float* W2 = (const float*)d_in[12];
  const float* b2 = (const float*)d_in[13];
  const float* A0 = (const float*)d_in[14];
  const float* A1 = (const float*)d_in[15];

  int N  = in_sizes[0] / 128;
  int N1 = in_sizes[1] / 128;
  int N2 = in_sizes[2] / 128;
  int E  = in_sizes[4];
  int M  = 2 * N;                    // CSR key space (both relations)

  float* out = (float*)d_out;
  size_t plane = (size_t)N * 64;
  float* h_tar  = out + 4 * plane;   // final value of plane 4 IS h_tar
  float* h_mask = out + plane;       // staged; finalize overwrites with mask1

  // Workspace (~90 MB; R0 validated ws_size >= ~126 MB)
  float* g1      = (float*)d_ws;               // N1*64
  float* g2      = g1 + (size_t)N1 * 64;       // N2*64
  float* avg1    = g2 + (size_t)N2 * 64;       // N*64
  float* avg2    = avg1 + (size_t)N * 64;      // N*64
  int*   cnt     = (int*)(avg2 + (size_t)N * 64);  // M
  int*   row_ptr = cnt + M;                    // M+1
  int*   cursor  = row_ptr + M + 1;            // M
  int*   partial = cursor + M;                 // <=256
  int*   nbr     = partial + 256;              // 2E
  ushort* frags  = (ushort*)(nbr + 2 * E);     // 32768 ushorts (64 KB)

  hipMemsetAsync(cnt, 0, (size_t)M * sizeof(int), stream);

  pack_frags_kernel<<<16, 256, 0, stream>>>(W0, W1, W2, A0, A1, frags);

  int t0 = N / 16, t1 = N1 / 16, t2 = N2 / 16;
  lin_elu_kernel<false><<<imin(2048, (t0 + 3) / 4), 256, 0, stream>>>(
      feats0, frags, b0, nullptr, h_tar, t0);
  lin_elu_kernel<false><<<imin(2048, (t0 + 3) / 4), 256, 0, stream>>>(
      maskf, frags, b0, nullptr, h_mask, t0);
  lin_elu_kernel<true><<<imin(2048, (t1 + 3) / 4), 256, 0, stream>>>(
      feats1, frags + 8192, b1, frags + 24576, g1, t1);
  lin_elu_kernel<true><<<imin(2048, (t2 + 3) / 4), 256, 0, stream>>>(
      feats2, frags + 16384, b2, frags + 28672, g2, t2);

  // CSR build
  count_kernel<<<(2 * E + 255) / 256, 256, 0, stream>>>(src1, src2, cnt, E, N);
  int nb = (M + 2047) / 2048;  // 98 for N=100000; fits single-block stage 2
  scan_sums_kernel<<<nb, 256, 0, stream>>>(cnt, partial, M);
  scan_partials_kernel<<<1, 256, 0, stream>>>(partial, row_ptr, nb, M);
  scan_write_kernel<<<nb, 256, 0, stream>>>(cnt, partial, row_ptr, cursor, M);
  // 8 key slices x 128 blocks each; slice = blockIdx&7 rides XCD round-robin
  bucket_kernel<<<1024, 256, 0, stream>>>(
      src1, dst1, src2, dst2, cursor, nbr, E, N);

  // Gather-mean
  aggregate_kernel<<<(M + 3) / 4, 256, 0, stream>>>(
      row_ptr, nbr, g1, g2, avg1, avg2, N);

  finalize_kernel<<<(N * 16 + 255) / 256, 256, 0, stream>>>(avg1, avg2, out, N);
}

// Round 3
// 613.396 us; speedup vs baseline: 1.3555x; 1.1152x over previous
//
#include <hip/hip_runtime.h>
#include <hip/hip_bf16.h>

// ---------------------------------------------------------------------------
// 2-relation GNN layer, fp32 in/out.
//   h_tar = elu(feats0@W0+b0)  -> written straight to out plane 4
//   h_mask = elu(mask@W0+b0)   -> staged in out plane 1
//   g1 = elu(feats1@W1+b1)@A0 ; g2 = elu(feats2@W2+b2)@A1   ((S/c)@A == (S@A)/c)
//   CSR build (count/scan/partition/scatter) over 2E edges, then gather-mean:
//   avg_r[v] = mean_{e: src_r[e]=v} g_r[dst_r[e]]
//   planes 0..3 = elu(t+avg1), elu(m+avg1), elu(t+avg2), elu(m+avg2)
// R2: 206M fp32 atomics = atomic wall (820us) -> CSR.
// R3: scattered 4B nbr stores: 211MB HBM writes for 12.8MB array (16x line
//     amplification). Key-sliced scatter (8 XCD slices): 295->135us but
//     WRITE stayed 208MB.
// R4: nt loads on edge streams: WRITE 208->163MB, dur unchanged. L2 does NOT
//     merge partial scatter lines (dirty-sector writeback, lines evicted
//     between same-line stores). Stop fighting cache policy.
// R5: replace scatter with partition+LDS-scatter: ALL global writes coalesced
//     by construction. Phase1: per-block counting sort of 8192-edge chunks
//     into 196 key-range buckets (packed 4B pairs, contiguous segment flush,
//     exact-fit regions from row_ptr). Phase2: per-bucket LDS image scatter,
//     coalesced nbr writeout.
// ---------------------------------------------------------------------------

typedef short  bf16x8 __attribute__((ext_vector_type(8)));
typedef float  f32x4  __attribute__((ext_vector_type(4)));
typedef int    i32x4  __attribute__((ext_vector_type(4)));

#define MFMA_BF16(a, b, c) __builtin_amdgcn_mfma_f32_16x16x32_bf16((a), (b), (c), 0, 0, 0)

__device__ __forceinline__ ushort f2bf(float f) {
  return (ushort)((__float_as_uint(f) + 0x8000u) >> 16);  // round-half-up, finite inputs
}
__device__ __forceinline__ float eluf(float x) {
  return x > 0.f ? x : (__expf(x) - 1.f);
}
// pack 8 consecutive fp32 -> bf16x8 (two aligned f32x4 loads)
__device__ __forceinline__ bf16x8 cvt8(const float* __restrict__ p) {
  f32x4 lo = *(const f32x4*)p;
  f32x4 hi = *(const f32x4*)(p + 4);
  union { unsigned u[4]; bf16x8 v; } r;
#pragma unroll
  for (int j = 0; j < 2; ++j) {
    unsigned a = __float_as_uint(lo[2 * j])     + 0x8000u;
    unsigned b = __float_as_uint(lo[2 * j + 1]) + 0x8000u;
    r.u[j] = (a >> 16) | (b & 0xFFFF0000u);
    unsigned c = __float_as_uint(hi[2 * j])     + 0x8000u;
    unsigned d = __float_as_uint(hi[2 * j + 1]) + 0x8000u;
    r.u[2 + j] = (c >> 16) | (d & 0xFFFF0000u);
  }
  return r.v;
}

// ---------------------------------------------------------------------------
// Pack fp32 W0/W1/W2 (128x64) and A0/A1 (64x64) into bf16 MFMA B-fragment
// order. Frag (kc,ct), lane l (q=l>>4, c=l&15): elem i = W[(kc*32+q*8+i)*64+ct*16+c]
// Layout: W0 @0 (16 frags*512), W1 @8192, W2 @16384, A0 @24576 (8), A1 @28672 (8)
// ---------------------------------------------------------------------------
__global__ __launch_bounds__(256) void pack_frags_kernel(
    const float* __restrict__ W0, const float* __restrict__ W1,
    const float* __restrict__ W2, const float* __restrict__ A0,
    const float* __restrict__ A1, ushort* __restrict__ out) {
  int gw   = (blockIdx.x * blockDim.x + threadIdx.x) >> 6;
  int lane = threadIdx.x & 63;
  if (gw >= 64) return;
  const float* src; ushort* dst; int f;
  if (gw < 16)      { src = W0; dst = out;         f = gw;      }
  else if (gw < 32) { src = W1; dst = out + 8192;  f = gw - 16; }
  else if (gw < 48) { src = W2; dst = out + 16384; f = gw - 32; }
  else if (gw < 56) { src = A0; dst = out + 24576; f = gw - 48; }
  else              { src = A1; dst = out + 28672; f = gw - 56; }
  int kc = f >> 2, ct = f & 3;
  int q = lane >> 4, c = lane & 15;
  ushort* d = dst + ((size_t)f * 64 + lane) * 8;
#pragma unroll
  for (int i = 0; i < 8; ++i)
    d[i] = f2bf(src[(kc * 32 + q * 8 + i) * 64 + ct * 16 + c]);
}

// ---------------------------------------------------------------------------
// Y = elu(X@W + b) [optionally @A] ; X: [M x 128] fp32, Y: [M x 64] fp32.
// One wave per 16-row tile. A-frag: m=lane&15, k=(lane>>4)*8+i (m89/m120);
// C/D: col=lane&15, row=(lane>>4)*4+reg (m89).
// ---------------------------------------------------------------------------
template <bool HASA>
__global__ __launch_bounds__(256) void lin_elu_kernel(
    const float* __restrict__ X, const ushort* __restrict__ Wp,
    const float* __restrict__ bias, const ushort* __restrict__ Ap,
    float* __restrict__ Y, int Mtiles) {
  __shared__ ushort plds[4][16 * 72];
  int lane  = threadIdx.x & 63;
  int q     = lane >> 4, c = lane & 15;
  int wslot = threadIdx.x >> 6;
  int wid   = blockIdx.x * 4 + wslot;
  int nw    = gridDim.x * 4;

  bf16x8 bw[4][4];
#pragma unroll
  for (int kc = 0; kc < 4; ++kc)
#pragma unroll
    for (int ct = 0; ct < 4; ++ct)
      bw[kc][ct] = *(const bf16x8*)(Wp + (((kc << 2) | ct) * 64 + lane) * 8);

  float bv[4];
#pragma unroll
  for (int ct = 0; ct < 4; ++ct) bv[ct] = bias[ct * 16 + c];

  bf16x8 ba[2][4];
  if (HASA) {
#pragma unroll
    for (int kc = 0; kc < 2; ++kc)
#pragma unroll
      for (int ct = 0; ct < 4; ++ct)
        ba[kc][ct] = *(const bf16x8*)(Ap + (((kc << 2) | ct) * 64 + lane) * 8);
  }

  ushort* myp = plds[wslot];

  for (int t = wid; t < Mtiles; t += nw) {
    const float* xr = X + ((size_t)(t * 16 + c)) * 128 + q * 8;
    bf16x8 a0 = cvt8(xr);
    bf16x8 a1 = cvt8(xr + 32);
    bf16x8 a2 = cvt8(xr + 64);
    bf16x8 a3 = cvt8(xr + 96);

    f32x4 acc[4];
#pragma unroll
    for (int ct = 0; ct < 4; ++ct) {
      f32x4 a = {0.f, 0.f, 0.f, 0.f};
      a = MFMA_BF16(a0, bw[0][ct], a);
      a = MFMA_BF16(a1, bw[1][ct], a);
      a = MFMA_BF16(a2, bw[2][ct], a);
      a = MFMA_BF16(a3, bw[3][ct], a);
      acc[ct] = a;
    }

    float* yr = Y + ((size_t)t * 16) * 64;
    if (!HASA) {
#pragma unroll
      for (int ct = 0; ct < 4; ++ct)
#pragma unroll
        for (int r = 0; r < 4; ++r)
          yr[(q * 4 + r) * 64 + ct * 16 + c] = eluf(acc[ct][r] + bv[ct]);
    } else {
      // stage elu'd tile as bf16 in wave-private LDS, reload as A-fragments
#pragma unroll
      for (int ct = 0; ct < 4; ++ct)
#pragma unroll
        for (int r = 0; r < 4; ++r)
          myp[(q * 4 + r) * 72 + ct * 16 + c] = f2bf(eluf(acc[ct][r] + bv[ct]));
      bf16x8 p0 = *(const bf16x8*)(myp + c * 72 + q * 8);
      bf16x8 p1 = *(const bf16x8*)(myp + c * 72 + 32 + q * 8);
      f32x4 acc2[4];
#pragma unroll
      for (int ct = 0; ct < 4; ++ct) {
        f32x4 a = {0.f, 0.f, 0.f, 0.f};
        a = MFMA_BF16(p0, ba[0][ct], a);
        a = MFMA_BF16(p1, ba[1][ct], a);
        acc2[ct] = a;
      }
#pragma unroll
      for (int ct = 0; ct < 4; ++ct)
#pragma unroll
        for (int r = 0; r < 4; ++r)
          yr[(q * 4 + r) * 64 + ct * 16 + c] = acc2[ct][r];
    }
  }
}

// ---------------------------------------------------------------------------
// CSR build. Key space: [0, 2N): relation1 nodes 0..N-1, relation2 N..2N-1.
// ---------------------------------------------------------------------------
__global__ __launch_bounds__(256) void count_kernel(
    const int* __restrict__ src1, const int* __restrict__ src2,
    int* __restrict__ cnt, int E, int N) {
  int e = blockIdx.x * blockDim.x + threadIdx.x;
  if (e < E)           atomicAdd(&cnt[__builtin_nontemporal_load(src1 + e)], 1);
  else if (e < 2 * E)  atomicAdd(&cnt[N + __builtin_nontemporal_load(src2 + e - E)], 1);
}

// scan stage 1: per-block (2048 elems) sums
__global__ __launch_bounds__(256) void scan_sums_kernel(
    const int* __restrict__ cnt, int* __restrict__ partial, int n) {
  __shared__ int lds[256];
  int t = threadIdx.x, base = blockIdx.x * 2048 + t * 8;
  int s = 0;
#pragma unroll
  for (int j = 0; j < 8; ++j) { int i = base + j; s += (i < n) ? cnt[i] : 0; }
  lds[t] = s; __syncthreads();
  for (int off = 128; off > 0; off >>= 1) {
    if (t < off) lds[t] += lds[t + off];
    __syncthreads();
  }
  if (t == 0) partial[blockIdx.x] = lds[0];
}

// scan stage 2: single-block exclusive scan of partials (nb <= 256);
// thread nb-1 also writes row_ptr[n] = grand total.
__global__ __launch_bounds__(256) void scan_partials_kernel(
    int* __restrict__ partial, int* __restrict__ row_ptr, int nb, int n) {
  __shared__ int lds[256];
  int t = threadIdx.x;
  int v = (t < nb) ? partial[t] : 0;
  lds[t] = v; __syncthreads();
  for (int off = 1; off < 256; off <<= 1) {
    int x = lds[t];
    int a = (t >= off) ? lds[t - off] : 0;
    __syncthreads();
    lds[t] = x + a;
    __syncthreads();
  }
  int incl = lds[t];
  if (t < nb) partial[t] = incl - v;          // exclusive
  if (t == nb - 1) row_ptr[n] = incl;          // total = 2E
}

// scan stage 3: recompute local sums, block-exclusive-scan thread sums,
// write row_ptr.
__global__ __launch_bounds__(256) void scan_write_kernel(
    const int* __restrict__ cnt, const int* __restrict__ partial,
    int* __restrict__ row_ptr, int n) {
  __shared__ int lds[256];
  int t = threadIdx.x, base = blockIdx.x * 2048 + t * 8;
  int c[8]; int s = 0;
#pragma unroll
  for (int j = 0; j < 8; ++j) { int i = base + j; c[j] = (i < n) ? cnt[i] : 0; s += c[j]; }
  lds[t] = s; __syncthreads();
  for (int off = 1; off < 256; off <<= 1) {
    int x = lds[t];
    int a = (t >= off) ? lds[t - off] : 0;
    __syncthreads();
    lds[t] = x + a;
    __syncthreads();
  }
  int run = partial[blockIdx.x] + lds[t] - s;  // exclusive prefix for this thread
#pragma unroll
  for (int j = 0; j < 8; ++j) {
    int i = base + j;
    if (i < n) row_ptr[i] = run;
    run += c[j];
  }
}

// bucket cursors = row_ptr at bucket boundaries (bucket = key>>10; pairs
// buffer shares nbr's CSR layout so per-bucket regions are an exact fit).
__global__ __launch_bounds__(256) void init_bcur_kernel(
    const int* __restrict__ row_ptr, int* __restrict__ bcur, int M) {
  int t = blockIdx.x * blockDim.x + threadIdx.x;
  int NB = (M + 1023) >> 10;
  if (t < NB) bcur[t] = row_ptr[t << 10];
}

// ---------------------------------------------------------------------------
// Phase 1: partition 8192-edge chunks into NB<=256 key-range buckets.
// Per block: LDS histogram -> LDS scan -> LDS counting-sort image of packed
// pairs ((key&1023)<<22 | dst, dst<2^22) -> per-bucket global range
// reservation (1 atomic per block per bucket) -> contiguous segment flush.
// All global writes are sequential runs (~42 pairs avg).
// ---------------------------------------------------------------------------
#define P1_CHUNK 8192
__global__ __launch_bounds__(256) void partition_kernel(
    const int* __restrict__ src1, const int* __restrict__ dst1,
    const int* __restrict__ src2, const int* __restrict__ dst2,
    int* __restrict__ bcur, unsigned* __restrict__ pairs, int E, int N) {
  __shared__ int hist[256], sbuf[256], lbase[256], lcur[256], gstart[256];
  __shared__ unsigned img[P1_CHUNK];
  int t  = threadIdx.x;
  int M  = 2 * N;
  int NB = (M + 1023) >> 10;
  int cb = blockIdx.x * P1_CHUNK;          // global edge base (< 2E, fits int)
  int ng = (2 * E - cb) >> 2;              // int4 groups left (2E, E mult of 4)
  if (ng > P1_CHUNK / 4) ng = P1_CHUNK / 4;

  hist[t] = 0;
  __syncthreads();

  // pass A: histogram (keys only)
  for (int i = t; i < ng; i += 256) {
    int e4 = cb + (i << 2);
    i32x4 k;
    if (e4 < E) k = *(const i32x4*)(src1 + e4);
    else {
      k = *(const i32x4*)(src2 + (e4 - E));
#pragma unroll
      for (int j = 0; j < 4; ++j) k[j] += N;
    }
#pragma unroll
    for (int j = 0; j < 4; ++j) atomicAdd(&hist[k[j] >> 10], 1);
  }
  __syncthreads();

  // exclusive scan of hist (Hillis-Steele over 256)
  sbuf[t] = hist[t];
  __syncthreads();
  for (int off = 1; off < 256; off <<= 1) {
    int x = sbuf[t];
    int a = (t >= off) ? sbuf[t - off] : 0;
    __syncthreads();
    sbuf[t] = x + a;
    __syncthreads();
  }
  lbase[t] = sbuf[t] - hist[t];
  lcur[t]  = sbuf[t] - hist[t];
  if (t < NB) gstart[t] = atomicAdd(&bcur[t], hist[t]);
  __syncthreads();

  // pass B: scatter packed pairs into LDS image grouped by bucket
  for (int i = t; i < ng; i += 256) {
    int e4 = cb + (i << 2);
    i32x4 k, v;
    if (e4 < E) {
      k = *(const i32x4*)(src1 + e4);
      v = *(const i32x4*)(dst1 + e4);
    } else {
      k = *(const i32x4*)(src2 + (e4 - E));
      v = *(const i32x4*)(dst2 + (e4 - E));
#pragma unroll
      for (int j = 0; j < 4; ++j) k[j] += N;
    }
#pragma unroll
    for (int j = 0; j < 4; ++j) {
      int b  = k[j] >> 10;
      int lp = atomicAdd(&lcur[b], 1);
      img[lp] = ((unsigned)(k[j] & 1023) << 22) | (unsigned)v[j];
    }
  }
  __syncthreads();

  // flush: wave w handles buckets w, w+4, ... ; each segment is contiguous
  int w = t >> 6, lane = t & 63;
  for (int b = w; b < NB; b += 4) {
    int len = hist[b], lb = lbase[b], gs = gstart[b];
    for (int i = lane; i < len; i += 64)
      pairs[gs + i] = img[lb + i];
  }
}

// ---------------------------------------------------------------------------
// Phase 2: one block per bucket (1024 keys). Per-key LDS cursors (from
// row_ptr), LDS-atomic scatter of the bucket's pairs into an LDS image,
// coalesced writeout to nbr. Overflow beyond P2_CAP (>+19 sigma, never in
// practice) falls back to direct global store -- correctness preserved.
// ---------------------------------------------------------------------------
#define P2_CAP 14848
__global__ __launch_bounds__(256) void scatter_kernel(
    const int* __restrict__ row_ptr, const unsigned* __restrict__ pairs,
    int* __restrict__ nbr, int M) {
  __shared__ int cur[1024];
  __shared__ int img[P2_CAP];
  int t     = threadIdx.x;
  int kbase = blockIdx.x << 10;
  int kend  = kbase + 1024; if (kend > M) kend = M;
  int kcnt  = kend - kbase;
  int pbase = row_ptr[kbase];
  int cnt   = row_ptr[kend] - pbase;

  for (int j = t; j < kcnt; j += 256) cur[j] = row_ptr[kbase + j] - pbase;
  __syncthreads();

  for (int i = t; i < cnt; i += 256) {
    unsigned p = pairs[pbase + i];
    int kl = (int)(p >> 22);
    int v  = (int)(p & 0x3FFFFFu);
    int pos = atomicAdd(&cur[kl], 1);
    if (pos < P2_CAP) img[pos] = v;
    else              nbr[pbase + pos] = v;
  }
  __syncthreads();

  int lim = cnt < P2_CAP ? cnt : P2_CAP;
  for (int i = t; i < lim; i += 256) nbr[pbase + i] = img[i];
}

// ---------------------------------------------------------------------------
// Gather-mean: one wave per key v in [0,2N). Lane j owns column j; each
// neighbor row is a 256B coalesced read from g (g1+g2 = 23MB, L2/L3-resident).
// avg = sum/deg (deg==0 -> 0), written dense -> finalize needs no counts.
// ---------------------------------------------------------------------------
__global__ __launch_bounds__(256) void aggregate_kernel(
    const int* __restrict__ row_ptr, const int* __restrict__ nbr,
    const float* __restrict__ g1, const float* __restrict__ g2,
    float* __restrict__ avg1, float* __restrict__ avg2, int N) {
  int lane = threadIdx.x & 63;
  int v = blockIdx.x * 4 + (threadIdx.x >> 6);
  if (v >= 2 * N) return;
  int n0 = row_ptr[v], n1 = row_ptr[v + 1];
  const float* __restrict__ g = (v < N) ? g1 : g2;
  float acc = 0.f;
  for (int base = n0; base < n1; base += 64) {
    int rem = n1 - base;
    int m = rem < 64 ? rem : 64;
    int idx = (lane < m) ? nbr[base + lane] : 0;
    int j = 0;
    for (; j + 4 <= m; j += 4) {  // 4 independent gathers in flight
      int d0 = __shfl(idx, j), d1 = __shfl(idx, j + 1);
      int d2 = __shfl(idx, j + 2), d3 = __shfl(idx, j + 3);
      float v0 = g[(size_t)d0 * 64 + lane];
      float v1 = g[(size_t)d1 * 64 + lane];
      float v2 = g[(size_t)d2 * 64 + lane];
      float v3 = g[(size_t)d3 * 64 + lane];
      acc += v0 + v1 + v2 + v3;
    }
    for (; j < m; ++j) {
      int d = __shfl(idx, j);
      acc += g[(size_t)d * 64 + lane];
    }
  }
  int deg = n1 - n0;
  float a = (deg > 0) ? acc / (float)deg : 0.f;
  if (v < N) avg1[(size_t)v * 64 + lane] = a;
  else       avg2[(size_t)(v - N) * 64 + lane] = a;
}

// ---------------------------------------------------------------------------
// Finalize: one thread per float4. t from out plane 4, m staged in plane 1.
// ---------------------------------------------------------------------------
__global__ __launch_bounds__(256) void finalize_kernel(
    const float* __restrict__ avg1, const float* __restrict__ avg2,
    float* __restrict__ out, int N) {
  int i = blockIdx.x * blockDim.x + threadIdx.x;
  if (i >= N * 16) return;
  size_t base  = ((size_t)i) << 2;
  size_t plane = (size_t)N * 64;
  f32x4 t = *(const f32x4*)(out + 4 * plane + base);
  f32x4 m = *(const f32x4*)(out + plane + base);
  f32x4 a1 = *(const f32x4*)(avg1 + base);
  f32x4 a2 = *(const f32x4*)(avg2 + base);
  f32x4 v1, m1, v2, m2;
#pragma unroll
  for (int j = 0; j < 4; ++j) {
    v1[j] = eluf(t[j] + a1[j]);
    m1[j] = eluf(m[j] + a1[j]);
    v2[j] = eluf(t[j] + a2[j]);
    m2[j] = eluf(m[j] + a2[j]);
  }
  *(f32x4*)(out + base)             = v1;
  *(f32x4*)(out + plane + base)     = m1;
  *(f32x4*)(out + 2 * plane + base) = v2;
  *(f32x4*)(out + 3 * plane + base) = m2;
}

static inline int imin(int a, int b) { return a < b ? a : b; }

extern "C" void kernel_launch(void* const* d_in, const int* in_sizes, int n_in,
                              void* d_out, int out_size, void* d_ws, size_t ws_size,
                              hipStream_t stream) {
  const float* feats0 = (const float*)d_in[0];
  const float* feats1 = (const float*)d_in[1];
  const float* feats2 = (const float*)d_in[2];
  const float* maskf  = (const float*)d_in[3];
  const int* src1 = (const int*)d_in[4];
  const int* dst1 = (const int*)d_in[5];
  const int* src2 = (const int*)d_in[6];
  const int* dst2 = (const int*)d_in[7];
  const float* W0 = (const float*)d_in[8];
  const float* b0 = (const float*)d_in[9];
  const float* W1 = (const float*)d_in[10];
  const float* b1 = (const float*)d_in[11];
  const float* W2 = (const float*)d_in[12];
  const float* b2 = (const float*)d_in[13];
  const float* A0 = (const float*)d_in[14];
  const float* A1 = (const float*)d_in[15];

  int N  = in_sizes[0] / 128;
  int N1 = in_sizes[1] / 128;
  int N2 = in_sizes[2] / 128;
  int E  = in_sizes[4];
  int M  = 2 * N;                    // CSR key space (both relations)

  float* out = (float*)d_out;
  size_t plane = (size_t)N * 64;
  float* h_tar  = out + 4 * plane;   // final value of plane 4 IS h_tar
  float* h_mask = out + plane;       // staged; finalize overwrites with mask1

  // Workspace (~104 MB; R0 validated ws_size >= ~126 MB)
  float* g1      = (float*)d_ws;               // N1*64
  float* g2      = g1 + (size_t)N1 * 64;       // N2*64
  float* avg1    = g2 + (size_t)N2 * 64;       // N*64
  float* avg2    = avg1 + (size_t)N * 64;      // N*64
  int*   cnt     = (int*)(avg2 + (size_t)N * 64);  // M
  int*   row_ptr = cnt + M;                    // M+1
  int*   bcur    = row_ptr + M + 1;            // 256
  int*   partial = bcur + 256;                 // <=256
  int*   nbr     = partial + 256;              // 2E
  unsigned* pairs = (unsigned*)(nbr + 2 * E);  // 2E
  ushort* frags  = (ushort*)(pairs + 2 * E);   // 32768 ushorts (64 KB)

  hipMemsetAsync(cnt, 0, (size_t)M * sizeof(int), stream);

  pack_frags_kernel<<<16, 256, 0, stream>>>(W0, W1, W2, A0, A1, frags);

  int t0 = N / 16, t1 = N1 / 16, t2 = N2 / 16;
  lin_elu_kernel<false><<<imin(2048, (t0 + 3) / 4), 256, 0, stream>>>(
      feats0, frags, b0, nullptr, h_tar, t0);
  lin_elu_kernel<false><<<imin(2048, (t0 + 3) / 4), 256, 0, stream>>>(
      maskf, frags, b0, nullptr, h_mask, t0);
  lin_elu_kernel<true><<<imin(2048, (t1 + 3) / 4), 256, 0, stream>>>(
      feats1, frags + 8192, b1, frags + 24576, g1, t1);
  lin_elu_kernel<true><<<imin(2048, (t2 + 3) / 4), 256, 0, stream>>>(
      feats2, frags + 16384, b2, frags + 28672, g2, t2);

  // CSR build: count -> scan -> partition -> per-bucket LDS scatter
  count_kernel<<<(2 * E + 255) / 256, 256, 0, stream>>>(src1, src2, cnt, E, N);
  int nb = (M + 2047) / 2048;  // 98 for N=100000; fits single-block stage 2
  scan_sums_kernel<<<nb, 256, 0, stream>>>(cnt, partial, M);
  scan_partials_kernel<<<1, 256, 0, stream>>>(partial, row_ptr, nb, M);
  scan_write_kernel<<<nb, 256, 0, stream>>>(cnt, partial, row_ptr, M);
  init_bcur_kernel<<<1, 256, 0, stream>>>(row_ptr, bcur, M);

  int NB = (M + 1023) >> 10;     // 196 buckets
  int p1blocks = (2 * E + P1_CHUNK - 1) / P1_CHUNK;   // 391 chunks
  partition_kernel<<<p1blocks, 256, 0, stream>>>(
      src1, dst1, src2, dst2, bcur, pairs, E, N);
  scatter_kernel<<<NB, 256, 0, stream>>>(row_ptr, pairs, nbr, M);

  // Gather-mean
  aggregate_kernel<<<(M + 3) / 4, 256, 0, stream>>>(
      row_ptr, nbr, g1, g2, avg1, avg2, N);

  finalize_kernel<<<(N * 16 + 255) / 256, 256, 0, stream>>>(avg1, avg2, out, N);
}

// Round 4
// 512.237 us; speedup vs baseline: 1.6232x; 1.1975x over previous
//
#include <hip/hip_runtime.h>
#include <hip/hip_bf16.h>

// ---------------------------------------------------------------------------
// 2-relation GNN layer, fp32 in/out.
//   h_tar = elu(feats0@W0+b0)  -> written straight to out plane 4
//   h_mask = elu(mask@W0+b0)   -> staged in out plane 1
//   g1 = elu(feats1@W1+b1)@A0 ; g2 = elu(feats2@W2+b2)@A1   ((S/c)@A == (S@A)/c)
//   Bucket partition (196 x 1024-key buckets) over 2E edges, per-bucket LDS
//   counting sort -> CSR (row_ptr + nbr), then gather-mean per node:
//   avg_r[v] = mean_{e: src_r[e]=v} g_r[dst_r[e]]
//   planes 0..3 = elu(t+avg1), elu(m+avg1), elu(t+avg2), elu(m+avg2)
// R2: 206M fp32 atomics = atomic wall (820us) -> CSR.
// R3: scattered 4B nbr stores: 211MB HBM writes for 12.8MB array (16x line
//     amplification); key-sliced scatter 295->135us but WRITE stayed 208MB.
// R4: nt loads didn't help (163MB): L2 does NOT merge partial scatter lines.
// R5: partition+LDS-scatter: all writes coalesced by construction. 613us.
//     BUG: P2_CAP 14848 < mean bucket load 16384 -> fallback ran ~10%.
// R6: count_kernel was top (127us, 99.8MB writes for 800KB cnt: atomic
//     writeback amplification). Per-key counts only fed row_ptr -> compute
//     row_ptr inside scatter_kernel (bucket pairs already in LDS; in-block
//     1024-key hist+scan, coalesced row_ptr write). Global side shrinks to
//     196 bucket totals (bucket_count + bscan). P2_CAP -> 18432 (+16 sigma).
// ---------------------------------------------------------------------------

typedef short  bf16x8 __attribute__((ext_vector_type(8)));
typedef float  f32x4  __attribute__((ext_vector_type(4)));
typedef int    i32x4  __attribute__((ext_vector_type(4)));

#define MFMA_BF16(a, b, c) __builtin_amdgcn_mfma_f32_16x16x32_bf16((a), (b), (c), 0, 0, 0)

__device__ __forceinline__ ushort f2bf(float f) {
  return (ushort)((__float_as_uint(f) + 0x8000u) >> 16);  // round-half-up, finite inputs
}
__device__ __forceinline__ float eluf(float x) {
  return x > 0.f ? x : (__expf(x) - 1.f);
}
// pack 8 consecutive fp32 -> bf16x8 (two aligned f32x4 loads)
__device__ __forceinline__ bf16x8 cvt8(const float* __restrict__ p) {
  f32x4 lo = *(const f32x4*)p;
  f32x4 hi = *(const f32x4*)(p + 4);
  union { unsigned u[4]; bf16x8 v; } r;
#pragma unroll
  for (int j = 0; j < 2; ++j) {
    unsigned a = __float_as_uint(lo[2 * j])     + 0x8000u;
    unsigned b = __float_as_uint(lo[2 * j + 1]) + 0x8000u;
    r.u[j] = (a >> 16) | (b & 0xFFFF0000u);
    unsigned c = __float_as_uint(hi[2 * j])     + 0x8000u;
    unsigned d = __float_as_uint(hi[2 * j + 1]) + 0x8000u;
    r.u[2 + j] = (c >> 16) | (d & 0xFFFF0000u);
  }
  return r.v;
}

// ---------------------------------------------------------------------------
// Pack fp32 W0/W1/W2 (128x64) and A0/A1 (64x64) into bf16 MFMA B-fragment
// order. Frag (kc,ct), lane l (q=l>>4, c=l&15): elem i = W[(kc*32+q*8+i)*64+ct*16+c]
// Layout: W0 @0 (16 frags*512), W1 @8192, W2 @16384, A0 @24576 (8), A1 @28672 (8)
// ---------------------------------------------------------------------------
__global__ __launch_bounds__(256) void pack_frags_kernel(
    const float* __restrict__ W0, const float* __restrict__ W1,
    const float* __restrict__ W2, const float* __restrict__ A0,
    const float* __restrict__ A1, ushort* __restrict__ out) {
  int gw   = (blockIdx.x * blockDim.x + threadIdx.x) >> 6;
  int lane = threadIdx.x & 63;
  if (gw >= 64) return;
  const float* src; ushort* dst; int f;
  if (gw < 16)      { src = W0; dst = out;         f = gw;      }
  else if (gw < 32) { src = W1; dst = out + 8192;  f = gw - 16; }
  else if (gw < 48) { src = W2; dst = out + 16384; f = gw - 32; }
  else if (gw < 56) { src = A0; dst = out + 24576; f = gw - 48; }
  else              { src = A1; dst = out + 28672; f = gw - 56; }
  int kc = f >> 2, ct = f & 3;
  int q = lane >> 4, c = lane & 15;
  ushort* d = dst + ((size_t)f * 64 + lane) * 8;
#pragma unroll
  for (int i = 0; i < 8; ++i)
    d[i] = f2bf(src[(kc * 32 + q * 8 + i) * 64 + ct * 16 + c]);
}

// ---------------------------------------------------------------------------
// Y = elu(X@W + b) [optionally @A] ; X: [M x 128] fp32, Y: [M x 64] fp32.
// One wave per 16-row tile. A-frag: m=lane&15, k=(lane>>4)*8+i (m89/m120);
// C/D: col=lane&15, row=(lane>>4)*4+reg (m89).
// ---------------------------------------------------------------------------
template <bool HASA>
__global__ __launch_bounds__(256) void lin_elu_kernel(
    const float* __restrict__ X, const ushort* __restrict__ Wp,
    const float* __restrict__ bias, const ushort* __restrict__ Ap,
    float* __restrict__ Y, int Mtiles) {
  __shared__ ushort plds[4][16 * 72];
  int lane  = threadIdx.x & 63;
  int q     = lane >> 4, c = lane & 15;
  int wslot = threadIdx.x >> 6;
  int wid   = blockIdx.x * 4 + wslot;
  int nw    = gridDim.x * 4;

  bf16x8 bw[4][4];
#pragma unroll
  for (int kc = 0; kc < 4; ++kc)
#pragma unroll
    for (int ct = 0; ct < 4; ++ct)
      bw[kc][ct] = *(const bf16x8*)(Wp + (((kc << 2) | ct) * 64 + lane) * 8);

  float bv[4];
#pragma unroll
  for (int ct = 0; ct < 4; ++ct) bv[ct] = bias[ct * 16 + c];

  bf16x8 ba[2][4];
  if (HASA) {
#pragma unroll
    for (int kc = 0; kc < 2; ++kc)
#pragma unroll
      for (int ct = 0; ct < 4; ++ct)
        ba[kc][ct] = *(const bf16x8*)(Ap + (((kc << 2) | ct) * 64 + lane) * 8);
  }

  ushort* myp = plds[wslot];

  for (int t = wid; t < Mtiles; t += nw) {
    const float* xr = X + ((size_t)(t * 16 + c)) * 128 + q * 8;
    bf16x8 a0 = cvt8(xr);
    bf16x8 a1 = cvt8(xr + 32);
    bf16x8 a2 = cvt8(xr + 64);
    bf16x8 a3 = cvt8(xr + 96);

    f32x4 acc[4];
#pragma unroll
    for (int ct = 0; ct < 4; ++ct) {
      f32x4 a = {0.f, 0.f, 0.f, 0.f};
      a = MFMA_BF16(a0, bw[0][ct], a);
      a = MFMA_BF16(a1, bw[1][ct], a);
      a = MFMA_BF16(a2, bw[2][ct], a);
      a = MFMA_BF16(a3, bw[3][ct], a);
      acc[ct] = a;
    }

    float* yr = Y + ((size_t)t * 16) * 64;
    if (!HASA) {
#pragma unroll
      for (int ct = 0; ct < 4; ++ct)
#pragma unroll
        for (int r = 0; r < 4; ++r)
          yr[(q * 4 + r) * 64 + ct * 16 + c] = eluf(acc[ct][r] + bv[ct]);
    } else {
      // stage elu'd tile as bf16 in wave-private LDS, reload as A-fragments
#pragma unroll
      for (int ct = 0; ct < 4; ++ct)
#pragma unroll
        for (int r = 0; r < 4; ++r)
          myp[(q * 4 + r) * 72 + ct * 16 + c] = f2bf(eluf(acc[ct][r] + bv[ct]));
      bf16x8 p0 = *(const bf16x8*)(myp + c * 72 + q * 8);
      bf16x8 p1 = *(const bf16x8*)(myp + c * 72 + 32 + q * 8);
      f32x4 acc2[4];
#pragma unroll
      for (int ct = 0; ct < 4; ++ct) {
        f32x4 a = {0.f, 0.f, 0.f, 0.f};
        a = MFMA_BF16(p0, ba[0][ct], a);
        a = MFMA_BF16(p1, ba[1][ct], a);
        acc2[ct] = a;
      }
#pragma unroll
      for (int ct = 0; ct < 4; ++ct)
#pragma unroll
        for (int r = 0; r < 4; ++r)
          yr[(q * 4 + r) * 64 + ct * 16 + c] = acc2[ct][r];
    }
  }
}

// ---------------------------------------------------------------------------
// Bucket-level counting (bucket = key>>10, NB<=256 buckets). LDS histogram
// per block, one global atomic per (block,bucket): ~100K atomics total vs
// 3.2M per-key atomics of the old count_kernel (which wrote 99.8MB HBM).
// ---------------------------------------------------------------------------
__global__ __launch_bounds__(256) void bucket_count_kernel(
    const int* __restrict__ src1, const int* __restrict__ src2,
    int* __restrict__ btot, int E, int N) {
  __shared__ int h[256];
  int t = threadIdx.x;
  h[t] = 0;
  __syncthreads();
  int n4 = (2 * E) >> 2;                  // E multiple of 4
  int stride = gridDim.x * blockDim.x;
  for (int i = blockIdx.x * blockDim.x + t; i < n4; i += stride) {
    int e4 = i << 2;
    i32x4 k;
    if (e4 < E) k = *(const i32x4*)(src1 + e4);
    else {
      k = *(const i32x4*)(src2 + (e4 - E));
#pragma unroll
      for (int j = 0; j < 4; ++j) k[j] += N;
    }
#pragma unroll
    for (int j = 0; j < 4; ++j) atomicAdd(&h[k[j] >> 10], 1);
  }
  __syncthreads();
  if (h[t]) atomicAdd(&btot[t], h[t]);
}

// single-block exclusive scan of bucket totals -> bstart, bcur; bstart[NB]=2E
__global__ __launch_bounds__(256) void bscan_kernel(
    const int* __restrict__ btot, int* __restrict__ bstart,
    int* __restrict__ bcur, int NB) {
  __shared__ int lds[256];
  int t = threadIdx.x;
  int v = (t < NB) ? btot[t] : 0;
  lds[t] = v; __syncthreads();
  for (int off = 1; off < 256; off <<= 1) {
    int x = lds[t];
    int a = (t >= off) ? lds[t - off] : 0;
    __syncthreads();
    lds[t] = x + a;
    __syncthreads();
  }
  int incl = lds[t];
  if (t < NB) { bstart[t] = incl - v; bcur[t] = incl - v; }
  if (t == NB - 1) bstart[NB] = incl;   // = 2E
}

// ---------------------------------------------------------------------------
// Phase 1: partition 8192-edge chunks into NB<=256 key-range buckets.
// Per block: LDS histogram -> LDS scan -> LDS counting-sort image of packed
// pairs ((key&1023)<<16 | dst, dst<2^16) -> per-bucket global range
// reservation (1 atomic per block per bucket) -> contiguous segment flush.
// All global writes are sequential runs (~42 pairs avg).
// ---------------------------------------------------------------------------
#define P1_CHUNK 8192
__global__ __launch_bounds__(256) void partition_kernel(
    const int* __restrict__ src1, const int* __restrict__ dst1,
    const int* __restrict__ src2, const int* __restrict__ dst2,
    int* __restrict__ bcur, unsigned* __restrict__ pairs, int E, int N) {
  __shared__ int hist[256], sbuf[256], lbase[256], lcur[256], gstart[256];
  __shared__ unsigned img[P1_CHUNK];
  int t  = threadIdx.x;
  int M  = 2 * N;
  int NB = (M + 1023) >> 10;
  int cb = blockIdx.x * P1_CHUNK;          // global edge base (< 2E, fits int)
  int ng = (2 * E - cb) >> 2;              // int4 groups left (2E, E mult of 4)
  if (ng > P1_CHUNK / 4) ng = P1_CHUNK / 4;

  hist[t] = 0;
  __syncthreads();

  // pass A: histogram (keys only)
  for (int i = t; i < ng; i += 256) {
    int e4 = cb + (i << 2);
    i32x4 k;
    if (e4 < E) k = *(const i32x4*)(src1 + e4);
    else {
      k = *(const i32x4*)(src2 + (e4 - E));
#pragma unroll
      for (int j = 0; j < 4; ++j) k[j] += N;
    }
#pragma unroll
    for (int j = 0; j < 4; ++j) atomicAdd(&hist[k[j] >> 10], 1);
  }
  __syncthreads();

  // exclusive scan of hist (Hillis-Steele over 256)
  sbuf[t] = hist[t];
  __syncthreads();
  for (int off = 1; off < 256; off <<= 1) {
    int x = sbuf[t];
    int a = (t >= off) ? sbuf[t - off] : 0;
    __syncthreads();
    sbuf[t] = x + a;
    __syncthreads();
  }
  lbase[t] = sbuf[t] - hist[t];
  lcur[t]  = sbuf[t] - hist[t];
  if (t < NB) gstart[t] = atomicAdd(&bcur[t], hist[t]);
  __syncthreads();

  // pass B: scatter packed pairs into LDS image grouped by bucket
  for (int i = t; i < ng; i += 256) {
    int e4 = cb + (i << 2);
    i32x4 k, v;
    if (e4 < E) {
      k = *(const i32x4*)(src1 + e4);
      v = *(const i32x4*)(dst1 + e4);
    } else {
      k = *(const i32x4*)(src2 + (e4 - E));
      v = *(const i32x4*)(dst2 + (e4 - E));
#pragma unroll
      for (int j = 0; j < 4; ++j) k[j] += N;
    }
#pragma unroll
    for (int j = 0; j < 4; ++j) {
      int b  = k[j] >> 10;
      int lp = atomicAdd(&lcur[b], 1);
      img[lp] = ((unsigned)(k[j] & 1023) << 16) | (unsigned)v[j];
    }
  }
  __syncthreads();

  // flush: wave w handles buckets w, w+4, ... ; each segment is contiguous
  int w = t >> 6, lane = t & 63;
  for (int b = w; b < NB; b += 4) {
    int len = hist[b], lb = lbase[b], gs = gstart[b];
    for (int i = lane; i < len; i += 64)
      pairs[gs + i] = img[lb + i];
  }
}

// ---------------------------------------------------------------------------
// Phase 2: one block per bucket (1024 keys). The bucket's pairs already sit
// contiguously in pairs[bstart[b]..bstart[b+1]). In-block: per-key LDS
// histogram -> 1024-wide scan (4 elems/thread + 256-thread Hillis-Steele)
// -> row_ptr writeout (coalesced) -> LDS-atomic counting-sort into img ->
// coalesced nbr writeout. P2_CAP = mean 16384 + 16 sigma; overflow falls
// back to direct global store (correctness preserved, ~never taken).
// ---------------------------------------------------------------------------
#define P2_CAP 18432
__global__ __launch_bounds__(256) void scatter_kernel(
    const int* __restrict__ bstart, const unsigned* __restrict__ pairs,
    int* __restrict__ row_ptr, int* __restrict__ nbr, int M) {
  __shared__ int cur[1024];
  __shared__ int ssum[256];
  __shared__ int img[P2_CAP];
  int t     = threadIdx.x;
  int b     = blockIdx.x;
  int kbase = b << 10;
  int kend  = kbase + 1024; if (kend > M) kend = M;
  int kcnt  = kend - kbase;
  int pbase = bstart[b];
  int cnt   = bstart[b + 1] - pbase;

  // per-key histogram of this bucket's pairs
#pragma unroll
  for (int j = 0; j < 4; ++j) cur[t * 4 + j] = 0;
  __syncthreads();
  for (int i = t; i < cnt; i += 256)
    atomicAdd(&cur[pairs[pbase + i] >> 16], 1);
  __syncthreads();

  // 1024-wide exclusive scan: 4 elems/thread, then scan 256 thread-sums
  int c0 = cur[t * 4], c1 = cur[t * 4 + 1], c2 = cur[t * 4 + 2], c3 = cur[t * 4 + 3];
  int s  = c0 + c1 + c2 + c3;
  ssum[t] = s;
  __syncthreads();
  for (int off = 1; off < 256; off <<= 1) {
    int x = ssum[t];
    int a = (t >= off) ? ssum[t - off] : 0;
    __syncthreads();
    ssum[t] = x + a;
    __syncthreads();
  }
  int run = ssum[t] - s;   // exclusive prefix of this thread's 4 keys
  int e0 = run, e1 = run + c0, e2 = e1 + c1, e3 = e2 + c2;
  cur[t * 4] = e0; cur[t * 4 + 1] = e1; cur[t * 4 + 2] = e2; cur[t * 4 + 3] = e3;
  // row_ptr writeout (coalesced 16B/thread)
  if (t * 4 + 3 < kcnt) {
    i32x4 rp = { pbase + e0, pbase + e1, pbase + e2, pbase + e3 };
    *(i32x4*)(row_ptr + kbase + t * 4) = rp;
  } else {
    if (t * 4     < kcnt) row_ptr[kbase + t * 4]     = pbase + e0;
    if (t * 4 + 1 < kcnt) row_ptr[kbase + t * 4 + 1] = pbase + e1;
    if (t * 4 + 2 < kcnt) row_ptr[kbase + t * 4 + 2] = pbase + e2;
    if (t * 4 + 3 < kcnt) row_ptr[kbase + t * 4 + 3] = pbase + e3;
  }
  if (t == 0 && kend == M) row_ptr[M] = pbase + cnt;
  __syncthreads();

  // counting-sort scatter into LDS image
  for (int i = t; i < cnt; i += 256) {
    unsigned p = pairs[pbase + i];
    int kl = (int)(p >> 16);
    int v  = (int)(p & 0xFFFFu);
    int pos = atomicAdd(&cur[kl], 1);
    if (pos < P2_CAP) img[pos] = v;
    else              nbr[pbase + pos] = v;
  }
  __syncthreads();

  int lim = cnt < P2_CAP ? cnt : P2_CAP;
  for (int i = t; i < lim; i += 256) nbr[pbase + i] = img[i];
}

// ---------------------------------------------------------------------------
// Gather-mean: one wave per key v in [0,2N). Lane j owns column j; each
// neighbor row is a 256B coalesced read from g (g1+g2 = 23MB, L2/L3-resident).
// avg = sum/deg (deg==0 -> 0), written dense -> finalize needs no counts.
// ---------------------------------------------------------------------------
__global__ __launch_bounds__(256) void aggregate_kernel(
    const int* __restrict__ row_ptr, const int* __restrict__ nbr,
    const float* __restrict__ g1, const float* __restrict__ g2,
    float* __restrict__ avg1, float* __restrict__ avg2, int N) {
  int lane = threadIdx.x & 63;
  int v = blockIdx.x * 4 + (threadIdx.x >> 6);
  if (v >= 2 * N) return;
  int n0 = row_ptr[v], n1 = row_ptr[v + 1];
  const float* __restrict__ g = (v < N) ? g1 : g2;
  float acc = 0.f;
  for (int base = n0; base < n1; base += 64) {
    int rem = n1 - base;
    int m = rem < 64 ? rem : 64;
    int idx = (lane < m) ? nbr[base + lane] : 0;
    int j = 0;
    for (; j + 4 <= m; j += 4) {  // 4 independent gathers in flight
      int d0 = __shfl(idx, j), d1 = __shfl(idx, j + 1);
      int d2 = __shfl(idx, j + 2), d3 = __shfl(idx, j + 3);
      float v0 = g[(size_t)d0 * 64 + lane];
      float v1 = g[(size_t)d1 * 64 + lane];
      float v2 = g[(size_t)d2 * 64 + lane];
      float v3 = g[(size_t)d3 * 64 + lane];
      acc += v0 + v1 + v2 + v3;
    }
    for (; j < m; ++j) {
      int d = __shfl(idx, j);
      acc += g[(size_t)d * 64 + lane];
    }
  }
  int deg = n1 - n0;
  float a = (deg > 0) ? acc / (float)deg : 0.f;
  if (v < N) avg1[(size_t)v * 64 + lane] = a;
  else       avg2[(size_t)(v - N) * 64 + lane] = a;
}

// ---------------------------------------------------------------------------
// Finalize: one thread per float4. t from out plane 4, m staged in plane 1.
// ---------------------------------------------------------------------------
__global__ __launch_bounds__(256) void finalize_kernel(
    const float* __restrict__ avg1, const float* __restrict__ avg2,
    float* __restrict__ out, int N) {
  int i = blockIdx.x * blockDim.x + threadIdx.x;
  if (i >= N * 16) return;
  size_t base  = ((size_t)i) << 2;
  size_t plane = (size_t)N * 64;
  f32x4 t = *(const f32x4*)(out + 4 * plane + base);
  f32x4 m = *(const f32x4*)(out + plane + base);
  f32x4 a1 = *(const f32x4*)(avg1 + base);
  f32x4 a2 = *(const f32x4*)(avg2 + base);
  f32x4 v1, m1, v2, m2;
#pragma unroll
  for (int j = 0; j < 4; ++j) {
    v1[j] = eluf(t[j] + a1[j]);
    m1[j] = eluf(m[j] + a1[j]);
    v2[j] = eluf(t[j] + a2[j]);
    m2[j] = eluf(m[j] + a2[j]);
  }
  *(f32x4*)(out + base)             = v1;
  *(f32x4*)(out + plane + base)     = m1;
  *(f32x4*)(out + 2 * plane + base) = v2;
  *(f32x4*)(out + 3 * plane + base) = m2;
}

static inline int imin(int a, int b) { return a < b ? a : b; }

extern "C" void kernel_launch(void* const* d_in, const int* in_sizes, int n_in,
                              void* d_out, int out_size, void* d_ws, size_t ws_size,
                              hipStream_t stream) {
  const float* feats0 = (const float*)d_in[0];
  const float* feats1 = (const float*)d_in[1];
  const float* feats2 = (const float*)d_in[2];
  const float* maskf  = (const float*)d_in[3];
  const int* src1 = (const int*)d_in[4];
  const int* dst1 = (const int*)d_in[5];
  const int* src2 = (const int*)d_in[6];
  const int* dst2 = (const int*)d_in[7];
  const float* W0 = (const float*)d_in[8];
  const float* b0 = (const float*)d_in[9];
  const float* W1 = (const float*)d_in[10];
  const float* b1 = (const float*)d_in[11];
  const float* W2 = (const float*)d_in[12];
  const float* b2 = (const float*)d_in[13];
  const float* A0 = (const float*)d_in[14];
  const float* A1 = (const float*)d_in[15];

  int N  = in_sizes[0] / 128;
  int N1 = in_sizes[1] / 128;
  int N2 = in_sizes[2] / 128;
  int E  = in_sizes[4];
  int M  = 2 * N;                    // CSR key space (both relations)

  float* out = (float*)d_out;
  size_t plane = (size_t)N * 64;
  float* h_tar  = out + 4 * plane;   // final value of plane 4 IS h_tar
  float* h_mask = out + plane;       // staged; finalize overwrites with mask1

  // Workspace (~100 MB; R0 validated ws_size >= ~126 MB)
  float* g1      = (float*)d_ws;               // N1*64
  float* g2      = g1 + (size_t)N1 * 64;       // N2*64
  float* avg1    = g2 + (size_t)N2 * 64;       // N*64
  float* avg2    = avg1 + (size_t)N * 64;      // N*64
  int*   row_ptr = (int*)(avg2 + (size_t)N * 64);  // M+1
  int*   btot    = row_ptr + M + 1;            // 256
  int*   bstart  = btot + 256;                 // 257
  int*   bcur    = bstart + 257;               // 256
  int*   nbr     = bcur + 256;                 // 2E
  unsigned* pairs = (unsigned*)(nbr + 2 * E);  // 2E
  ushort* frags  = (ushort*)(pairs + 2 * E);   // 32768 ushorts (64 KB)

  hipMemsetAsync(btot, 0, 256 * sizeof(int), stream);

  pack_frags_kernel<<<16, 256, 0, stream>>>(W0, W1, W2, A0, A1, frags);

  int t0 = N / 16, t1 = N1 / 16, t2 = N2 / 16;
  lin_elu_kernel<false><<<imin(2048, (t0 + 3) / 4), 256, 0, stream>>>(
      feats0, frags, b0, nullptr, h_tar, t0);
  lin_elu_kernel<false><<<imin(2048, (t0 + 3) / 4), 256, 0, stream>>>(
      maskf, frags, b0, nullptr, h_mask, t0);
  lin_elu_kernel<true><<<imin(2048, (t1 + 3) / 4), 256, 0, stream>>>(
      feats1, frags + 8192, b1, frags + 24576, g1, t1);
  lin_elu_kernel<true><<<imin(2048, (t2 + 3) / 4), 256, 0, stream>>>(
      feats2, frags + 16384, b2, frags + 28672, g2, t2);

  // CSR build: bucket-count -> bucket-scan -> partition -> per-bucket sort
  int NB = (M + 1023) >> 10;     // 196 buckets
  bucket_count_kernel<<<512, 256, 0, stream>>>(src1, src2, btot, E, N);
  bscan_kernel<<<1, 256, 0, stream>>>(btot, bstart, bcur, NB);

  int p1blocks = (2 * E + P1_CHUNK - 1) / P1_CHUNK;   // 391 chunks
  partition_kernel<<<p1blocks, 256, 0, stream>>>(
      src1, dst1, src2, dst2, bcur, pairs, E, N);
  scatter_kernel<<<NB, 256, 0, stream>>>(bstart, pairs, row_ptr, nbr, M);

  // Gather-mean
  aggregate_kernel<<<(M + 3) / 4, 256, 0, stream>>>(
      row_ptr, nbr, g1, g2, avg1, avg2, N);

  finalize_kernel<<<(N * 16 + 255) / 256, 256, 0, stream>>>(avg1, avg2, out, N);
}

// Round 5
// 484.116 us; speedup vs baseline: 1.7175x; 1.0581x over previous
//
#include <hip/hip_runtime.h>
#include <hip/hip_bf16.h>

// ---------------------------------------------------------------------------
// 2-relation GNN layer, fp32 in/out.
//   h_tar = elu(feats0@W0+b0)  -> written straight to out plane 4
//   h_mask = elu(mask@W0+b0)   -> staged in out plane 1
//   g1 = elu(feats1@W1+b1)@A0 ; g2 = elu(feats2@W2+b2)@A1   ((S/c)@A == (S@A)/c)
//   Bucket partition (196 x 1024-key buckets) over 2E edges, per-bucket LDS
//   counting sort -> CSR (row_ptr + nbr), then gather-mean per node:
//   avg_r[v] = mean_{e: src_r[e]=v} g_r[dst_r[e]]
//   planes 0..3 = elu(t+avg1), elu(m+avg1), elu(t+avg2), elu(m+avg2)
// R2: 206M fp32 atomics = atomic wall (820us) -> CSR.
// R3/R4: scattered 4B stores = 16x HBM write amplification; L2 will not merge
//     partial lines (key-slicing + nt loads both failed to fix WRITE).
// R5: partition+LDS-scatter: all global writes coalesced by construction.
// R6: per-key count atomics (99.8MB writeback for 800KB cnt) -> row_ptr is
//     now computed inside scatter_kernel; global side = 196 bucket totals.
// R7: aggregate was top (103us, FETCH 273MB: 816MB of 256B-row gathers over
//     23MB g, L2 catches ~2/3). Bytes-cut: g and avg in bf16 (halves every
//     tier of gather traffic; adds <=1e-3 error vs 0.0156 margin) + 2 edges
//     per wave-iter (32 lanes x ushort2 per row) to halve per-edge VALU.
// ---------------------------------------------------------------------------

typedef short  bf16x8 __attribute__((ext_vector_type(8)));
typedef float  f32x4  __attribute__((ext_vector_type(4)));
typedef int    i32x4  __attribute__((ext_vector_type(4)));

#define MFMA_BF16(a, b, c) __builtin_amdgcn_mfma_f32_16x16x32_bf16((a), (b), (c), 0, 0, 0)

__device__ __forceinline__ ushort f2bf(float f) {
  return (ushort)((__float_as_uint(f) + 0x8000u) >> 16);  // round-half-up, finite inputs
}
__device__ __forceinline__ float eluf(float x) {
  return x > 0.f ? x : (__expf(x) - 1.f);
}
__device__ __forceinline__ float bflo(unsigned u) { return __uint_as_float(u << 16); }
__device__ __forceinline__ float bfhi(unsigned u) { return __uint_as_float(u & 0xFFFF0000u); }
// pack 8 consecutive fp32 -> bf16x8 (two aligned f32x4 loads)
__device__ __forceinline__ bf16x8 cvt8(const float* __restrict__ p) {
  f32x4 lo = *(const f32x4*)p;
  f32x4 hi = *(const f32x4*)(p + 4);
  union { unsigned u[4]; bf16x8 v; } r;
#pragma unroll
  for (int j = 0; j < 2; ++j) {
    unsigned a = __float_as_uint(lo[2 * j])     + 0x8000u;
    unsigned b = __float_as_uint(lo[2 * j + 1]) + 0x8000u;
    r.u[j] = (a >> 16) | (b & 0xFFFF0000u);
    unsigned c = __float_as_uint(hi[2 * j])     + 0x8000u;
    unsigned d = __float_as_uint(hi[2 * j + 1]) + 0x8000u;
    r.u[2 + j] = (c >> 16) | (d & 0xFFFF0000u);
  }
  return r.v;
}

// ---------------------------------------------------------------------------
// Pack fp32 W0/W1/W2 (128x64) and A0/A1 (64x64) into bf16 MFMA B-fragment
// order. Frag (kc,ct), lane l (q=l>>4, c=l&15): elem i = W[(kc*32+q*8+i)*64+ct*16+c]
// Layout: W0 @0 (16 frags*512), W1 @8192, W2 @16384, A0 @24576 (8), A1 @28672 (8)
// ---------------------------------------------------------------------------
__global__ __launch_bounds__(256) void pack_frags_kernel(
    const float* __restrict__ W0, const float* __restrict__ W1,
    const float* __restrict__ W2, const float* __restrict__ A0,
    const float* __restrict__ A1, ushort* __restrict__ out) {
  int gw   = (blockIdx.x * blockDim.x + threadIdx.x) >> 6;
  int lane = threadIdx.x & 63;
  if (gw >= 64) return;
  const float* src; ushort* dst; int f;
  if (gw < 16)      { src = W0; dst = out;         f = gw;      }
  else if (gw < 32) { src = W1; dst = out + 8192;  f = gw - 16; }
  else if (gw < 48) { src = W2; dst = out + 16384; f = gw - 32; }
  else if (gw < 56) { src = A0; dst = out + 24576; f = gw - 48; }
  else              { src = A1; dst = out + 28672; f = gw - 56; }
  int kc = f >> 2, ct = f & 3;
  int q = lane >> 4, c = lane & 15;
  ushort* d = dst + ((size_t)f * 64 + lane) * 8;
#pragma unroll
  for (int i = 0; i < 8; ++i)
    d[i] = f2bf(src[(kc * 32 + q * 8 + i) * 64 + ct * 16 + c]);
}

// ---------------------------------------------------------------------------
// Y = elu(X@W + b) [optionally @A] ; X: [M x 128] fp32.
// HASA=false: Y fp32 [M x 64]. HASA=true: Y bf16 [M x 64] (gather operand).
// One wave per 16-row tile. A-frag: m=lane&15, k=(lane>>4)*8+i (m89/m120);
// C/D: col=lane&15, row=(lane>>4)*4+reg (m89).
// ---------------------------------------------------------------------------
template <bool HASA>
__global__ __launch_bounds__(256) void lin_elu_kernel(
    const float* __restrict__ X, const ushort* __restrict__ Wp,
    const float* __restrict__ bias, const ushort* __restrict__ Ap,
    void* __restrict__ Yv, int Mtiles) {
  __shared__ ushort plds[4][16 * 72];
  int lane  = threadIdx.x & 63;
  int q     = lane >> 4, c = lane & 15;
  int wslot = threadIdx.x >> 6;
  int wid   = blockIdx.x * 4 + wslot;
  int nw    = gridDim.x * 4;

  bf16x8 bw[4][4];
#pragma unroll
  for (int kc = 0; kc < 4; ++kc)
#pragma unroll
    for (int ct = 0; ct < 4; ++ct)
      bw[kc][ct] = *(const bf16x8*)(Wp + (((kc << 2) | ct) * 64 + lane) * 8);

  float bv[4];
#pragma unroll
  for (int ct = 0; ct < 4; ++ct) bv[ct] = bias[ct * 16 + c];

  bf16x8 ba[2][4];
  if (HASA) {
#pragma unroll
    for (int kc = 0; kc < 2; ++kc)
#pragma unroll
      for (int ct = 0; ct < 4; ++ct)
        ba[kc][ct] = *(const bf16x8*)(Ap + (((kc << 2) | ct) * 64 + lane) * 8);
  }

  ushort* myp = plds[wslot];

  for (int t = wid; t < Mtiles; t += nw) {
    const float* xr = X + ((size_t)(t * 16 + c)) * 128 + q * 8;
    bf16x8 a0 = cvt8(xr);
    bf16x8 a1 = cvt8(xr + 32);
    bf16x8 a2 = cvt8(xr + 64);
    bf16x8 a3 = cvt8(xr + 96);

    f32x4 acc[4];
#pragma unroll
    for (int ct = 0; ct < 4; ++ct) {
      f32x4 a = {0.f, 0.f, 0.f, 0.f};
      a = MFMA_BF16(a0, bw[0][ct], a);
      a = MFMA_BF16(a1, bw[1][ct], a);
      a = MFMA_BF16(a2, bw[2][ct], a);
      a = MFMA_BF16(a3, bw[3][ct], a);
      acc[ct] = a;
    }

    if (!HASA) {
      float* yr = (float*)Yv + ((size_t)t * 16) * 64;
#pragma unroll
      for (int ct = 0; ct < 4; ++ct)
#pragma unroll
        for (int r = 0; r < 4; ++r)
          yr[(q * 4 + r) * 64 + ct * 16 + c] = eluf(acc[ct][r] + bv[ct]);
    } else {
      // stage elu'd tile as bf16 in wave-private LDS, reload as A-fragments
#pragma unroll
      for (int ct = 0; ct < 4; ++ct)
#pragma unroll
        for (int r = 0; r < 4; ++r)
          myp[(q * 4 + r) * 72 + ct * 16 + c] = f2bf(eluf(acc[ct][r] + bv[ct]));
      bf16x8 p0 = *(const bf16x8*)(myp + c * 72 + q * 8);
      bf16x8 p1 = *(const bf16x8*)(myp + c * 72 + 32 + q * 8);
      f32x4 acc2[4];
#pragma unroll
      for (int ct = 0; ct < 4; ++ct) {
        f32x4 a = {0.f, 0.f, 0.f, 0.f};
        a = MFMA_BF16(p0, ba[0][ct], a);
        a = MFMA_BF16(p1, ba[1][ct], a);
        acc2[ct] = a;
      }
      ushort* yb = (ushort*)Yv + ((size_t)t * 16) * 64;
#pragma unroll
      for (int ct = 0; ct < 4; ++ct)
#pragma unroll
        for (int r = 0; r < 4; ++r)
          yb[(q * 4 + r) * 64 + ct * 16 + c] = f2bf(acc2[ct][r]);
    }
  }
}

// ---------------------------------------------------------------------------
// Bucket-level counting (bucket = key>>10, NB<=256 buckets). LDS histogram
// per block, one global atomic per (block,bucket).
// ---------------------------------------------------------------------------
__global__ __launch_bounds__(256) void bucket_count_kernel(
    const int* __restrict__ src1, const int* __restrict__ src2,
    int* __restrict__ btot, int E, int N) {
  __shared__ int h[256];
  int t = threadIdx.x;
  h[t] = 0;
  __syncthreads();
  int n4 = (2 * E) >> 2;                  // E multiple of 4
  int stride = gridDim.x * blockDim.x;
  for (int i = blockIdx.x * blockDim.x + t; i < n4; i += stride) {
    int e4 = i << 2;
    i32x4 k;
    if (e4 < E) k = *(const i32x4*)(src1 + e4);
    else {
      k = *(const i32x4*)(src2 + (e4 - E));
#pragma unroll
      for (int j = 0; j < 4; ++j) k[j] += N;
    }
#pragma unroll
    for (int j = 0; j < 4; ++j) atomicAdd(&h[k[j] >> 10], 1);
  }
  __syncthreads();
  if (h[t]) atomicAdd(&btot[t], h[t]);
}

// single-block exclusive scan of bucket totals -> bstart, bcur; bstart[NB]=2E
__global__ __launch_bounds__(256) void bscan_kernel(
    const int* __restrict__ btot, int* __restrict__ bstart,
    int* __restrict__ bcur, int NB) {
  __shared__ int lds[256];
  int t = threadIdx.x;
  int v = (t < NB) ? btot[t] : 0;
  lds[t] = v; __syncthreads();
  for (int off = 1; off < 256; off <<= 1) {
    int x = lds[t];
    int a = (t >= off) ? lds[t - off] : 0;
    __syncthreads();
    lds[t] = x + a;
    __syncthreads();
  }
  int incl = lds[t];
  if (t < NB) { bstart[t] = incl - v; bcur[t] = incl - v; }
  if (t == NB - 1) bstart[NB] = incl;   // = 2E
}

// ---------------------------------------------------------------------------
// Phase 1: partition 8192-edge chunks into NB<=256 key-range buckets.
// Per block: LDS histogram -> LDS scan -> LDS counting-sort image of packed
// pairs ((key&1023)<<16 | dst, dst<2^16) -> per-bucket global range
// reservation (1 atomic per block per bucket) -> contiguous segment flush.
// ---------------------------------------------------------------------------
#define P1_CHUNK 8192
__global__ __launch_bounds__(256) void partition_kernel(
    const int* __restrict__ src1, const int* __restrict__ dst1,
    const int* __restrict__ src2, const int* __restrict__ dst2,
    int* __restrict__ bcur, unsigned* __restrict__ pairs, int E, int N) {
  __shared__ int hist[256], sbuf[256], lbase[256], lcur[256], gstart[256];
  __shared__ unsigned img[P1_CHUNK];
  int t  = threadIdx.x;
  int M  = 2 * N;
  int NB = (M + 1023) >> 10;
  int cb = blockIdx.x * P1_CHUNK;          // global edge base (< 2E, fits int)
  int ng = (2 * E - cb) >> 2;              // int4 groups left (2E, E mult of 4)
  if (ng > P1_CHUNK / 4) ng = P1_CHUNK / 4;

  hist[t] = 0;
  __syncthreads();

  // pass A: histogram (keys only)
  for (int i = t; i < ng; i += 256) {
    int e4 = cb + (i << 2);
    i32x4 k;
    if (e4 < E) k = *(const i32x4*)(src1 + e4);
    else {
      k = *(const i32x4*)(src2 + (e4 - E));
#pragma unroll
      for (int j = 0; j < 4; ++j) k[j] += N;
    }
#pragma unroll
    for (int j = 0; j < 4; ++j) atomicAdd(&hist[k[j] >> 10], 1);
  }
  __syncthreads();

  // exclusive scan of hist (Hillis-Steele over 256)
  sbuf[t] = hist[t];
  __syncthreads();
  for (int off = 1; off < 256; off <<= 1) {
    int x = sbuf[t];
    int a = (t >= off) ? sbuf[t - off] : 0;
    __syncthreads();
    sbuf[t] = x + a;
    __syncthreads();
  }
  lbase[t] = sbuf[t] - hist[t];
  lcur[t]  = sbuf[t] - hist[t];
  if (t < NB) gstart[t] = atomicAdd(&bcur[t], hist[t]);
  __syncthreads();

  // pass B: scatter packed pairs into LDS image grouped by bucket
  for (int i = t; i < ng; i += 256) {
    int e4 = cb + (i << 2);
    i32x4 k, v;
    if (e4 < E) {
      k = *(const i32x4*)(src1 + e4);
      v = *(const i32x4*)(dst1 + e4);
    } else {
      k = *(const i32x4*)(src2 + (e4 - E));
      v = *(const i32x4*)(dst2 + (e4 - E));
#pragma unroll
      for (int j = 0; j < 4; ++j) k[j] += N;
    }
#pragma unroll
    for (int j = 0; j < 4; ++j) {
      int b  = k[j] >> 10;
      int lp = atomicAdd(&lcur[b], 1);
      img[lp] = ((unsigned)(k[j] & 1023) << 16) | (unsigned)v[j];
    }
  }
  __syncthreads();

  // flush: wave w handles buckets w, w+4, ... ; each segment is contiguous
  int w = t >> 6, lane = t & 63;
  for (int b = w; b < NB; b += 4) {
    int len = hist[b], lb = lbase[b], gs = gstart[b];
    for (int i = lane; i < len; i += 64)
      pairs[gs + i] = img[lb + i];
  }
}

// ---------------------------------------------------------------------------
// Phase 2: one block per bucket (1024 keys). In-block: per-key LDS histogram
// -> 1024-wide scan -> row_ptr writeout (coalesced) -> LDS-atomic counting
// sort into img -> coalesced nbr writeout. P2_CAP = mean 16384 + 16 sigma;
// overflow falls back to direct global store (correctness preserved).
// ---------------------------------------------------------------------------
#define P2_CAP 18432
__global__ __launch_bounds__(256) void scatter_kernel(
    const int* __restrict__ bstart, const unsigned* __restrict__ pairs,
    int* __restrict__ row_ptr, int* __restrict__ nbr, int M) {
  __shared__ int cur[1024];
  __shared__ int ssum[256];
  __shared__ int img[P2_CAP];
  int t     = threadIdx.x;
  int b     = blockIdx.x;
  int kbase = b << 10;
  int kend  = kbase + 1024; if (kend > M) kend = M;
  int kcnt  = kend - kbase;
  int pbase = bstart[b];
  int cnt   = bstart[b + 1] - pbase;

  // per-key histogram of this bucket's pairs
#pragma unroll
  for (int j = 0; j < 4; ++j) cur[t * 4 + j] = 0;
  __syncthreads();
  for (int i = t; i < cnt; i += 256)
    atomicAdd(&cur[pairs[pbase + i] >> 16], 1);
  __syncthreads();

  // 1024-wide exclusive scan: 4 elems/thread, then scan 256 thread-sums
  int c0 = cur[t * 4], c1 = cur[t * 4 + 1], c2 = cur[t * 4 + 2], c3 = cur[t * 4 + 3];
  int s  = c0 + c1 + c2 + c3;
  ssum[t] = s;
  __syncthreads();
  for (int off = 1; off < 256; off <<= 1) {
    int x = ssum[t];
    int a = (t >= off) ? ssum[t - off] : 0;
    __syncthreads();
    ssum[t] = x + a;
    __syncthreads();
  }
  int run = ssum[t] - s;   // exclusive prefix of this thread's 4 keys
  int e0 = run, e1 = run + c0, e2 = e1 + c1, e3 = e2 + c2;
  cur[t * 4] = e0; cur[t * 4 + 1] = e1; cur[t * 4 + 2] = e2; cur[t * 4 + 3] = e3;
  // row_ptr writeout (coalesced 16B/thread)
  if (t * 4 + 3 < kcnt) {
    i32x4 rp = { pbase + e0, pbase + e1, pbase + e2, pbase + e3 };
    *(i32x4*)(row_ptr + kbase + t * 4) = rp;
  } else {
    if (t * 4     < kcnt) row_ptr[kbase + t * 4]     = pbase + e0;
    if (t * 4 + 1 < kcnt) row_ptr[kbase + t * 4 + 1] = pbase + e1;
    if (t * 4 + 2 < kcnt) row_ptr[kbase + t * 4 + 2] = pbase + e2;
    if (t * 4 + 3 < kcnt) row_ptr[kbase + t * 4 + 3] = pbase + e3;
  }
  if (t == 0 && kend == M) row_ptr[M] = pbase + cnt;
  __syncthreads();

  // counting-sort scatter into LDS image
  for (int i = t; i < cnt; i += 256) {
    unsigned p = pairs[pbase + i];
    int kl = (int)(p >> 16);
    int v  = (int)(p & 0xFFFFu);
    int pos = atomicAdd(&cur[kl], 1);
    if (pos < P2_CAP) img[pos] = v;
    else              nbr[pbase + pos] = v;
  }
  __syncthreads();

  int lim = cnt < P2_CAP ? cnt : P2_CAP;
  for (int i = t; i < lim; i += 256) nbr[pbase + i] = img[i];
}

// ---------------------------------------------------------------------------
// Gather-mean over bf16 g: one wave per key v. 2 edges per iteration:
// half = lane>>5 picks the edge, 32 lanes x ushort2 cover the 64-col row
// (128B coalesced per row). fp32 accumulate; halves combined via
// __shfl_xor(32); bf16 avg writeout (ushort2 per lane, 128B per row).
// ---------------------------------------------------------------------------
__global__ __launch_bounds__(256) void aggregate_kernel(
    const int* __restrict__ row_ptr, const int* __restrict__ nbr,
    const ushort* __restrict__ g1, const ushort* __restrict__ g2,
    ushort* __restrict__ avg1, ushort* __restrict__ avg2, int N) {
  int lane = threadIdx.x & 63;
  int v = blockIdx.x * 4 + (threadIdx.x >> 6);
  if (v >= 2 * N) return;
  int n0 = row_ptr[v], n1 = row_ptr[v + 1];
  const ushort* __restrict__ g = (v < N) ? g1 : g2;
  int half = lane >> 5;
  int c2   = (lane & 31) << 1;
  float ax = 0.f, ay = 0.f;
  for (int base = n0; base < n1; base += 64) {
    int rem = n1 - base;
    int m = rem < 64 ? rem : 64;
    int idx = (lane < m) ? nbr[base + lane] : 0;
    int j = 0;
    for (; j + 8 <= m; j += 8) {   // 8 edges: 4 independent 2-row loads
      int d0 = __shfl(idx, j + half);
      int d1 = __shfl(idx, j + 2 + half);
      int d2 = __shfl(idx, j + 4 + half);
      int d3 = __shfl(idx, j + 6 + half);
      unsigned u0 = *(const unsigned*)(g + (size_t)d0 * 64 + c2);
      unsigned u1 = *(const unsigned*)(g + (size_t)d1 * 64 + c2);
      unsigned u2 = *(const unsigned*)(g + (size_t)d2 * 64 + c2);
      unsigned u3 = *(const unsigned*)(g + (size_t)d3 * 64 + c2);
      ax += bflo(u0) + bflo(u1) + bflo(u2) + bflo(u3);
      ay += bfhi(u0) + bfhi(u1) + bfhi(u2) + bfhi(u3);
    }
    for (; j < m; j += 2) {
      int jj = j + half;
      int d = __shfl(idx, jj);           // jj>=m pulls idx[jj]=0: safe row
      unsigned u = *(const unsigned*)(g + (size_t)d * 64 + c2);
      if (jj < m) { ax += bflo(u); ay += bfhi(u); }
    }
  }
  ax += __shfl_xor(ax, 32);
  ay += __shfl_xor(ay, 32);
  if (lane < 32) {
    int deg = n1 - n0;
    float s = (deg > 0) ? 1.f / (float)deg : 0.f;
    unsigned w = (unsigned)f2bf(ax * s) | ((unsigned)f2bf(ay * s) << 16);
    ushort* av = (v < N) ? avg1 : avg2;
    int vv = (v < N) ? v : v - N;
    *(unsigned*)(av + (size_t)vv * 64 + c2) = w;
  }
}

// ---------------------------------------------------------------------------
// Finalize: one thread per float4. t from out plane 4, m staged in plane 1.
// avg read as bf16 (4B per 2 cols).
// ---------------------------------------------------------------------------
__global__ __launch_bounds__(256) void finalize_kernel(
    const ushort* __restrict__ avg1, const ushort* __restrict__ avg2,
    float* __restrict__ out, int N) {
  int i = blockIdx.x * blockDim.x + threadIdx.x;
  if (i >= N * 16) return;
  size_t base  = ((size_t)i) << 2;
  size_t plane = (size_t)N * 64;
  f32x4 t = *(const f32x4*)(out + 4 * plane + base);
  f32x4 m = *(const f32x4*)(out + plane + base);
  unsigned a1l = *(const unsigned*)(avg1 + base);
  unsigned a1h = *(const unsigned*)(avg1 + base + 2);
  unsigned a2l = *(const unsigned*)(avg2 + base);
  unsigned a2h = *(const unsigned*)(avg2 + base + 2);
  float a1[4] = { bflo(a1l), bfhi(a1l), bflo(a1h), bfhi(a1h) };
  float a2[4] = { bflo(a2l), bfhi(a2l), bflo(a2h), bfhi(a2h) };
  f32x4 v1, m1, v2, m2;
#pragma unroll
  for (int j = 0; j < 4; ++j) {
    v1[j] = eluf(t[j] + a1[j]);
    m1[j] = eluf(m[j] + a1[j]);
    v2[j] = eluf(t[j] + a2[j]);
    m2[j] = eluf(m[j] + a2[j]);
  }
  *(f32x4*)(out + base)             = v1;
  *(f32x4*)(out + plane + base)     = m1;
  *(f32x4*)(out + 2 * plane + base) = v2;
  *(f32x4*)(out + 3 * plane + base) = m2;
}

static inline int imin(int a, int b) { return a < b ? a : b; }

extern "C" void kernel_launch(void* const* d_in, const int* in_sizes, int n_in,
                              void* d_out, int out_size, void* d_ws, size_t ws_size,
                              hipStream_t stream) {
  const float* feats0 = (const float*)d_in[0];
  const float* feats1 = (const float*)d_in[1];
  const float* feats2 = (const float*)d_in[2];
  const float* maskf  = (const float*)d_in[3];
  const int* src1 = (const int*)d_in[4];
  const int* dst1 = (const int*)d_in[5];
  const int* src2 = (const int*)d_in[6];
  const int* dst2 = (const int*)d_in[7];
  const float* W0 = (const float*)d_in[8];
  const float* b0 = (const float*)d_in[9];
  const float* W1 = (const float*)d_in[10];
  const float* b1 = (const float*)d_in[11];
  const float* W2 = (const float*)d_in[12];
  const float* b2 = (const float*)d_in[13];
  const float* A0 = (const float*)d_in[14];
  const float* A1 = (const float*)d_in[15];

  int N  = in_sizes[0] / 128;
  int N1 = in_sizes[1] / 128;
  int N2 = in_sizes[2] / 128;
  int E  = in_sizes[4];
  int M  = 2 * N;                    // CSR key space (both relations)

  float* out = (float*)d_out;
  size_t plane = (size_t)N * 64;
  float* h_tar  = out + 4 * plane;   // final value of plane 4 IS h_tar
  float* h_mask = out + plane;       // staged; finalize overwrites with mask1

  // Workspace (~90 MB; validated ws_size >= ~126 MB). frags first (16B align)
  ushort* frags  = (ushort*)d_ws;              // 32768 ushorts (64 KB)
  int* row_ptr   = (int*)((char*)d_ws + 65536);    // M+1
  int* btot      = row_ptr + M + 1;            // 256
  int* bstart    = btot + 256;                 // 257
  int* bcur      = bstart + 257;               // 256
  int* nbr       = bcur + 256;                 // 2E
  unsigned* pairs = (unsigned*)(nbr + 2 * E);  // 2E
  ushort* g1b    = (ushort*)(pairs + 2 * E);   // N1*64
  ushort* g2b    = g1b + (size_t)N1 * 64;      // N2*64
  ushort* avg1b  = g2b + (size_t)N2 * 64;      // N*64
  ushort* avg2b  = avg1b + (size_t)N * 64;     // N*64

  hipMemsetAsync(btot, 0, 256 * sizeof(int), stream);

  pack_frags_kernel<<<16, 256, 0, stream>>>(W0, W1, W2, A0, A1, frags);

  int t0 = N / 16, t1 = N1 / 16, t2 = N2 / 16;
  lin_elu_kernel<false><<<imin(2048, (t0 + 3) / 4), 256, 0, stream>>>(
      feats0, frags, b0, nullptr, h_tar, t0);
  lin_elu_kernel<false><<<imin(2048, (t0 + 3) / 4), 256, 0, stream>>>(
      maskf, frags, b0, nullptr, h_mask, t0);
  lin_elu_kernel<true><<<imin(2048, (t1 + 3) / 4), 256, 0, stream>>>(
      feats1, frags + 8192, b1, frags + 24576, g1b, t1);
  lin_elu_kernel<true><<<imin(2048, (t2 + 3) / 4), 256, 0, stream>>>(
      feats2, frags + 16384, b2, frags + 28672, g2b, t2);

  // CSR build: bucket-count -> bucket-scan -> partition -> per-bucket sort
  int NB = (M + 1023) >> 10;     // 196 buckets
  bucket_count_kernel<<<512, 256, 0, stream>>>(src1, src2, btot, E, N);
  bscan_kernel<<<1, 256, 0, stream>>>(btot, bstart, bcur, NB);

  int p1blocks = (2 * E + P1_CHUNK - 1) / P1_CHUNK;   // 391 chunks
  partition_kernel<<<p1blocks, 256, 0, stream>>>(
      src1, dst1, src2, dst2, bcur, pairs, E, N);
  scatter_kernel<<<NB, 256, 0, stream>>>(bstart, pairs, row_ptr, nbr, M);

  // Gather-mean (bf16 rows, 2 edges/iter)
  aggregate_kernel<<<(M + 3) / 4, 256, 0, stream>>>(
      row_ptr, nbr, g1b, g2b, avg1b, avg2b, N);

  finalize_kernel<<<(N * 16 + 255) / 256, 256, 0, stream>>>(avg1b, avg2b, out, N);
}

// Round 6
// 456.595 us; speedup vs baseline: 1.8210x; 1.0603x over previous
//
#include <hip/hip_runtime.h>
#include <hip/hip_bf16.h>

// ---------------------------------------------------------------------------
// 2-relation GNN layer, fp32 in/out.
//   h_tar = elu(feats0@W0+b0)  -> written straight to out plane 4
//   h_mask = elu(mask@W0+b0)   -> staged in out plane 1
//   g1 = elu(feats1@W1+b1)@A0 ; g2 = elu(feats2@W2+b2)@A1   ((S/c)@A == (S@A)/c)
//   Bucket partition (196 x 1024-key buckets) over 2E edges, per-bucket LDS
//   counting sort -> CSR (row_ptr + nbr), then fused gather-mean + epilogue:
//   planes 0..3 = elu(t+avg1), elu(m+avg1), elu(t+avg2), elu(m+avg2)
// R2: 206M fp32 atomics = atomic wall -> CSR.
// R3/R4: scattered 4B stores = 16x HBM write amplification; L2 will not merge
//     partial lines (key-slicing + nt loads both failed to fix WRITE).
// R5: partition+LDS-scatter: all global writes coalesced by construction.
// R6: per-key count atomics -> row_ptr computed inside scatter_kernel.
// R7: g/avg in bf16 + 2-edge gather: FETCH 273->146MB, 103->83us. VALUBusy
//     rose to 59%, HBM 27% -> VALU/latency-bound, not bytes.
// R8: octet gather (8 lanes x uint4 per row: 1 shfl + 1 dwordx4 per 8 edges,
//     ~2x fewer VALU/edge, 4x load ILP) + fuse finalize into aggregate (wave
//     owns node v, does both relations, stages means in wave-private LDS,
//     writes 4 planes coalesced; kills avg round-trip + a launch).
// ---------------------------------------------------------------------------

typedef short  bf16x8 __attribute__((ext_vector_type(8)));
typedef float  f32x4  __attribute__((ext_vector_type(4)));
typedef int    i32x4  __attribute__((ext_vector_type(4)));
typedef unsigned u32x4 __attribute__((ext_vector_type(4)));

#define MFMA_BF16(a, b, c) __builtin_amdgcn_mfma_f32_16x16x32_bf16((a), (b), (c), 0, 0, 0)

__device__ __forceinline__ ushort f2bf(float f) {
  return (ushort)((__float_as_uint(f) + 0x8000u) >> 16);  // round-half-up, finite inputs
}
__device__ __forceinline__ float eluf(float x) {
  return x > 0.f ? x : (__expf(x) - 1.f);
}
__device__ __forceinline__ float bflo(unsigned u) { return __uint_as_float(u << 16); }
__device__ __forceinline__ float bfhi(unsigned u) { return __uint_as_float(u & 0xFFFF0000u); }
// pack 8 consecutive fp32 -> bf16x8 (two aligned f32x4 loads)
__device__ __forceinline__ bf16x8 cvt8(const float* __restrict__ p) {
  f32x4 lo = *(const f32x4*)p;
  f32x4 hi = *(const f32x4*)(p + 4);
  union { unsigned u[4]; bf16x8 v; } r;
#pragma unroll
  for (int j = 0; j < 2; ++j) {
    unsigned a = __float_as_uint(lo[2 * j])     + 0x8000u;
    unsigned b = __float_as_uint(lo[2 * j + 1]) + 0x8000u;
    r.u[j] = (a >> 16) | (b & 0xFFFF0000u);
    unsigned c = __float_as_uint(hi[2 * j])     + 0x8000u;
    unsigned d = __float_as_uint(hi[2 * j + 1]) + 0x8000u;
    r.u[2 + j] = (c >> 16) | (d & 0xFFFF0000u);
  }
  return r.v;
}

// ---------------------------------------------------------------------------
// Pack fp32 W0/W1/W2 (128x64) and A0/A1 (64x64) into bf16 MFMA B-fragment
// order. Frag (kc,ct), lane l (q=l>>4, c=l&15): elem i = W[(kc*32+q*8+i)*64+ct*16+c]
// Layout: W0 @0 (16 frags*512), W1 @8192, W2 @16384, A0 @24576 (8), A1 @28672 (8)
// ---------------------------------------------------------------------------
__global__ __launch_bounds__(256) void pack_frags_kernel(
    const float* __restrict__ W0, const float* __restrict__ W1,
    const float* __restrict__ W2, const float* __restrict__ A0,
    const float* __restrict__ A1, ushort* __restrict__ out) {
  int gw   = (blockIdx.x * blockDim.x + threadIdx.x) >> 6;
  int lane = threadIdx.x & 63;
  if (gw >= 64) return;
  const float* src; ushort* dst; int f;
  if (gw < 16)      { src = W0; dst = out;         f = gw;      }
  else if (gw < 32) { src = W1; dst = out + 8192;  f = gw - 16; }
  else if (gw < 48) { src = W2; dst = out + 16384; f = gw - 32; }
  else if (gw < 56) { src = A0; dst = out + 24576; f = gw - 48; }
  else              { src = A1; dst = out + 28672; f = gw - 56; }
  int kc = f >> 2, ct = f & 3;
  int q = lane >> 4, c = lane & 15;
  ushort* d = dst + ((size_t)f * 64 + lane) * 8;
#pragma unroll
  for (int i = 0; i < 8; ++i)
    d[i] = f2bf(src[(kc * 32 + q * 8 + i) * 64 + ct * 16 + c]);
}

// ---------------------------------------------------------------------------
// Y = elu(X@W + b) [optionally @A] ; X: [M x 128] fp32.
// HASA=false: Y fp32 [M x 64]. HASA=true: Y bf16 [M x 64] (gather operand).
// One wave per 16-row tile. A-frag: m=lane&15, k=(lane>>4)*8+i (m89/m120);
// C/D: col=lane&15, row=(lane>>4)*4+reg (m89).
// ---------------------------------------------------------------------------
template <bool HASA>
__global__ __launch_bounds__(256) void lin_elu_kernel(
    const float* __restrict__ X, const ushort* __restrict__ Wp,
    const float* __restrict__ bias, const ushort* __restrict__ Ap,
    void* __restrict__ Yv, int Mtiles) {
  __shared__ ushort plds[4][16 * 72];
  int lane  = threadIdx.x & 63;
  int q     = lane >> 4, c = lane & 15;
  int wslot = threadIdx.x >> 6;
  int wid   = blockIdx.x * 4 + wslot;
  int nw    = gridDim.x * 4;

  bf16x8 bw[4][4];
#pragma unroll
  for (int kc = 0; kc < 4; ++kc)
#pragma unroll
    for (int ct = 0; ct < 4; ++ct)
      bw[kc][ct] = *(const bf16x8*)(Wp + (((kc << 2) | ct) * 64 + lane) * 8);

  float bv[4];
#pragma unroll
  for (int ct = 0; ct < 4; ++ct) bv[ct] = bias[ct * 16 + c];

  bf16x8 ba[2][4];
  if (HASA) {
#pragma unroll
    for (int kc = 0; kc < 2; ++kc)
#pragma unroll
      for (int ct = 0; ct < 4; ++ct)
        ba[kc][ct] = *(const bf16x8*)(Ap + (((kc << 2) | ct) * 64 + lane) * 8);
  }

  ushort* myp = plds[wslot];

  for (int t = wid; t < Mtiles; t += nw) {
    const float* xr = X + ((size_t)(t * 16 + c)) * 128 + q * 8;
    bf16x8 a0 = cvt8(xr);
    bf16x8 a1 = cvt8(xr + 32);
    bf16x8 a2 = cvt8(xr + 64);
    bf16x8 a3 = cvt8(xr + 96);

    f32x4 acc[4];
#pragma unroll
    for (int ct = 0; ct < 4; ++ct) {
      f32x4 a = {0.f, 0.f, 0.f, 0.f};
      a = MFMA_BF16(a0, bw[0][ct], a);
      a = MFMA_BF16(a1, bw[1][ct], a);
      a = MFMA_BF16(a2, bw[2][ct], a);
      a = MFMA_BF16(a3, bw[3][ct], a);
      acc[ct] = a;
    }

    if (!HASA) {
      float* yr = (float*)Yv + ((size_t)t * 16) * 64;
#pragma unroll
      for (int ct = 0; ct < 4; ++ct)
#pragma unroll
        for (int r = 0; r < 4; ++r)
          yr[(q * 4 + r) * 64 + ct * 16 + c] = eluf(acc[ct][r] + bv[ct]);
    } else {
      // stage elu'd tile as bf16 in wave-private LDS, reload as A-fragments
#pragma unroll
      for (int ct = 0; ct < 4; ++ct)
#pragma unroll
        for (int r = 0; r < 4; ++r)
          myp[(q * 4 + r) * 72 + ct * 16 + c] = f2bf(eluf(acc[ct][r] + bv[ct]));
      bf16x8 p0 = *(const bf16x8*)(myp + c * 72 + q * 8);
      bf16x8 p1 = *(const bf16x8*)(myp + c * 72 + 32 + q * 8);
      f32x4 acc2[4];
#pragma unroll
      for (int ct = 0; ct < 4; ++ct) {
        f32x4 a = {0.f, 0.f, 0.f, 0.f};
        a = MFMA_BF16(p0, ba[0][ct], a);
        a = MFMA_BF16(p1, ba[1][ct], a);
        acc2[ct] = a;
      }
      ushort* yb = (ushort*)Yv + ((size_t)t * 16) * 64;
#pragma unroll
      for (int ct = 0; ct < 4; ++ct)
#pragma unroll
        for (int r = 0; r < 4; ++r)
          yb[(q * 4 + r) * 64 + ct * 16 + c] = f2bf(acc2[ct][r]);
    }
  }
}

// ---------------------------------------------------------------------------
// Bucket-level counting (bucket = key>>10, NB<=256 buckets). LDS histogram
// per block, one global atomic per (block,bucket).
// ---------------------------------------------------------------------------
__global__ __launch_bounds__(256) void bucket_count_kernel(
    const int* __restrict__ src1, const int* __restrict__ src2,
    int* __restrict__ btot, int E, int N) {
  __shared__ int h[256];
  int t = threadIdx.x;
  h[t] = 0;
  __syncthreads();
  int n4 = (2 * E) >> 2;                  // E multiple of 4
  int stride = gridDim.x * blockDim.x;
  for (int i = blockIdx.x * blockDim.x + t; i < n4; i += stride) {
    int e4 = i << 2;
    i32x4 k;
    if (e4 < E) k = *(const i32x4*)(src1 + e4);
    else {
      k = *(const i32x4*)(src2 + (e4 - E));
#pragma unroll
      for (int j = 0; j < 4; ++j) k[j] += N;
    }
#pragma unroll
    for (int j = 0; j < 4; ++j) atomicAdd(&h[k[j] >> 10], 1);
  }
  __syncthreads();
  if (h[t]) atomicAdd(&btot[t], h[t]);
}

// single-block exclusive scan of bucket totals -> bstart, bcur; bstart[NB]=2E
__global__ __launch_bounds__(256) void bscan_kernel(
    const int* __restrict__ btot, int* __restrict__ bstart,
    int* __restrict__ bcur, int NB) {
  __shared__ int lds[256];
  int t = threadIdx.x;
  int v = (t < NB) ? btot[t] : 0;
  lds[t] = v; __syncthreads();
  for (int off = 1; off < 256; off <<= 1) {
    int x = lds[t];
    int a = (t >= off) ? lds[t - off] : 0;
    __syncthreads();
    lds[t] = x + a;
    __syncthreads();
  }
  int incl = lds[t];
  if (t < NB) { bstart[t] = incl - v; bcur[t] = incl - v; }
  if (t == NB - 1) bstart[NB] = incl;   // = 2E
}

// ---------------------------------------------------------------------------
// Phase 1: partition 8192-edge chunks into NB<=256 key-range buckets.
// Per block: LDS histogram -> LDS scan -> LDS counting-sort image of packed
// pairs ((key&1023)<<16 | dst, dst<2^16) -> per-bucket global range
// reservation (1 atomic per block per bucket) -> contiguous segment flush.
// ---------------------------------------------------------------------------
#define P1_CHUNK 8192
__global__ __launch_bounds__(256) void partition_kernel(
    const int* __restrict__ src1, const int* __restrict__ dst1,
    const int* __restrict__ src2, const int* __restrict__ dst2,
    int* __restrict__ bcur, unsigned* __restrict__ pairs, int E, int N) {
  __shared__ int hist[256], sbuf[256], lbase[256], lcur[256], gstart[256];
  __shared__ unsigned img[P1_CHUNK];
  int t  = threadIdx.x;
  int M  = 2 * N;
  int NB = (M + 1023) >> 10;
  int cb = blockIdx.x * P1_CHUNK;          // global edge base (< 2E, fits int)
  int ng = (2 * E - cb) >> 2;              // int4 groups left (2E, E mult of 4)
  if (ng > P1_CHUNK / 4) ng = P1_CHUNK / 4;

  hist[t] = 0;
  __syncthreads();

  // pass A: histogram (keys only)
  for (int i = t; i < ng; i += 256) {
    int e4 = cb + (i << 2);
    i32x4 k;
    if (e4 < E) k = *(const i32x4*)(src1 + e4);
    else {
      k = *(const i32x4*)(src2 + (e4 - E));
#pragma unroll
      for (int j = 0; j < 4; ++j) k[j] += N;
    }
#pragma unroll
    for (int j = 0; j < 4; ++j) atomicAdd(&hist[k[j] >> 10], 1);
  }
  __syncthreads();

  // exclusive scan of hist (Hillis-Steele over 256)
  sbuf[t] = hist[t];
  __syncthreads();
  for (int off = 1; off < 256; off <<= 1) {
    int x = sbuf[t];
    int a = (t >= off) ? sbuf[t - off] : 0;
    __syncthreads();
    sbuf[t] = x + a;
    __syncthreads();
  }
  lbase[t] = sbuf[t] - hist[t];
  lcur[t]  = sbuf[t] - hist[t];
  if (t < NB) gstart[t] = atomicAdd(&bcur[t], hist[t]);
  __syncthreads();

  // pass B: scatter packed pairs into LDS image grouped by bucket
  for (int i = t; i < ng; i += 256) {
    int e4 = cb + (i << 2);
    i32x4 k, v;
    if (e4 < E) {
      k = *(const i32x4*)(src1 + e4);
      v = *(const i32x4*)(dst1 + e4);
    } else {
      k = *(const i32x4*)(src2 + (e4 - E));
      v = *(const i32x4*)(dst2 + (e4 - E));
#pragma unroll
      for (int j = 0; j < 4; ++j) k[j] += N;
    }
#pragma unroll
    for (int j = 0; j < 4; ++j) {
      int b  = k[j] >> 10;
      int lp = atomicAdd(&lcur[b], 1);
      img[lp] = ((unsigned)(k[j] & 1023) << 16) | (unsigned)v[j];
    }
  }
  __syncthreads();

  // flush: wave w handles buckets w, w+4, ... ; each segment is contiguous
  int w = t >> 6, lane = t & 63;
  for (int b = w; b < NB; b += 4) {
    int len = hist[b], lb = lbase[b], gs = gstart[b];
    for (int i = lane; i < len; i += 64)
      pairs[gs + i] = img[lb + i];
  }
}

// ---------------------------------------------------------------------------
// Phase 2: one block per bucket (1024 keys). In-block: per-key LDS histogram
// -> 1024-wide scan -> row_ptr writeout (coalesced) -> LDS-atomic counting
// sort into img -> coalesced nbr writeout. P2_CAP = mean 16384 + 16 sigma;
// overflow falls back to direct global store (correctness preserved).
// ---------------------------------------------------------------------------
#define P2_CAP 18432
__global__ __launch_bounds__(256) void scatter_kernel(
    const int* __restrict__ bstart, const unsigned* __restrict__ pairs,
    int* __restrict__ row_ptr, int* __restrict__ nbr, int M) {
  __shared__ int cur[1024];
  __shared__ int ssum[256];
  __shared__ int img[P2_CAP];
  int t     = threadIdx.x;
  int b     = blockIdx.x;
  int kbase = b << 10;
  int kend  = kbase + 1024; if (kend > M) kend = M;
  int kcnt  = kend - kbase;
  int pbase = bstart[b];
  int cnt   = bstart[b + 1] - pbase;

  // per-key histogram of this bucket's pairs
#pragma unroll
  for (int j = 0; j < 4; ++j) cur[t * 4 + j] = 0;
  __syncthreads();
  for (int i = t; i < cnt; i += 256)
    atomicAdd(&cur[pairs[pbase + i] >> 16], 1);
  __syncthreads();

  // 1024-wide exclusive scan: 4 elems/thread, then scan 256 thread-sums
  int c0 = cur[t * 4], c1 = cur[t * 4 + 1], c2 = cur[t * 4 + 2], c3 = cur[t * 4 + 3];
  int s  = c0 + c1 + c2 + c3;
  ssum[t] = s;
  __syncthreads();
  for (int off = 1; off < 256; off <<= 1) {
    int x = ssum[t];
    int a = (t >= off) ? ssum[t - off] : 0;
    __syncthreads();
    ssum[t] = x + a;
    __syncthreads();
  }
  int run = ssum[t] - s;   // exclusive prefix of this thread's 4 keys
  int e0 = run, e1 = run + c0, e2 = e1 + c1, e3 = e2 + c2;
  cur[t * 4] = e0; cur[t * 4 + 1] = e1; cur[t * 4 + 2] = e2; cur[t * 4 + 3] = e3;
  // row_ptr writeout (coalesced 16B/thread)
  if (t * 4 + 3 < kcnt) {
    i32x4 rp = { pbase + e0, pbase + e1, pbase + e2, pbase + e3 };
    *(i32x4*)(row_ptr + kbase + t * 4) = rp;
  } else {
    if (t * 4     < kcnt) row_ptr[kbase + t * 4]     = pbase + e0;
    if (t * 4 + 1 < kcnt) row_ptr[kbase + t * 4 + 1] = pbase + e1;
    if (t * 4 + 2 < kcnt) row_ptr[kbase + t * 4 + 2] = pbase + e2;
    if (t * 4 + 3 < kcnt) row_ptr[kbase + t * 4 + 3] = pbase + e3;
  }
  if (t == 0 && kend == M) row_ptr[M] = pbase + cnt;
  __syncthreads();

  // counting-sort scatter into LDS image
  for (int i = t; i < cnt; i += 256) {
    unsigned p = pairs[pbase + i];
    int kl = (int)(p >> 16);
    int v  = (int)(p & 0xFFFFu);
    int pos = atomicAdd(&cur[kl], 1);
    if (pos < P2_CAP) img[pos] = v;
    else              nbr[pbase + pos] = v;
  }
  __syncthreads();

  int lim = cnt < P2_CAP ? cnt : P2_CAP;
  for (int i = t; i < lim; i += 256) nbr[pbase + i] = img[i];
}

// ---------------------------------------------------------------------------
// Fused gather-mean + epilogue. One wave per node v: processes relation-1 row
// (key v, from g1) and relation-2 row (key N+v, from g2).
// Octet layout: e8 = lane>>3 picks 1 of 8 edges, g8 = lane&7 picks the 16B
// col-group -> one shfl + one dwordx4 load serves 8 edges (full 128B row per
// lane-octet, coalesced). Cross-octet reduce: 3x shfl_xor. Means staged in
// wave-private LDS, then all 64 lanes do the elu-combine and write planes
// 0..3 coalesced (4B/lane). Plane 4 (h_tar) already final from lin_elu.
// ---------------------------------------------------------------------------
__global__ __launch_bounds__(256) void agg_final_kernel(
    const int* __restrict__ row_ptr, const int* __restrict__ nbr,
    const ushort* __restrict__ g1, const ushort* __restrict__ g2,
    float* __restrict__ out, int N) {
  __shared__ float sh[4][2][64];
  int lane  = threadIdx.x & 63;
  int wslot = threadIdx.x >> 6;
  int v = blockIdx.x * 4 + wslot;
  if (v >= N) return;
  int e8  = lane >> 3;
  int lgo = (lane & 7) << 4;     // byte offset of this lane's 16B col-group

#pragma unroll
  for (int r = 0; r < 2; ++r) {
    int key = v + r * N;
    int n0 = row_ptr[key], n1 = row_ptr[key + 1];
    const char* gb = (const char*)(r ? g2 : g1);
    float acc[8];
#pragma unroll
    for (int c = 0; c < 8; ++c) acc[c] = 0.f;

    for (int base = n0; base < n1; base += 64) {
      int m = n1 - base; if (m > 64) m = 64;
      int idx = (lane < m) ? nbr[base + lane] : 0;
      int j = 0;
      for (; j + 16 <= m; j += 16) {     // 2 octets in flight
        int d0 = __shfl(idx, j + e8);
        int d1 = __shfl(idx, j + 8 + e8);
        u32x4 u0 = *(const u32x4*)(gb + (unsigned)((d0 << 7) + lgo));
        u32x4 u1 = *(const u32x4*)(gb + (unsigned)((d1 << 7) + lgo));
#pragma unroll
        for (int c = 0; c < 4; ++c) {
          acc[2 * c]     += bflo(u0[c]) + bflo(u1[c]);
          acc[2 * c + 1] += bfhi(u0[c]) + bfhi(u1[c]);
        }
      }
      if (j + 8 <= m) {
        int d0 = __shfl(idx, j + e8);
        u32x4 u0 = *(const u32x4*)(gb + (unsigned)((d0 << 7) + lgo));
#pragma unroll
        for (int c = 0; c < 4; ++c) {
          acc[2 * c]     += bflo(u0[c]);
          acc[2 * c + 1] += bfhi(u0[c]);
        }
        j += 8;
      }
      if (j < m) {                        // masked tail octet
        int jj = j + e8;
        int d0 = __shfl(idx, jj & 63);    // idx[jj]=0 for jj>=m (safe row)
        u32x4 u0 = *(const u32x4*)(gb + (unsigned)((d0 << 7) + lgo));
        if (jj < m) {
#pragma unroll
          for (int c = 0; c < 4; ++c) {
            acc[2 * c]     += bflo(u0[c]);
            acc[2 * c + 1] += bfhi(u0[c]);
          }
        }
      }
    }

    // reduce across the 8 edge-octets
#pragma unroll
    for (int c = 0; c < 8; ++c) {
      acc[c] += __shfl_xor(acc[c], 8);
      acc[c] += __shfl_xor(acc[c], 16);
      acc[c] += __shfl_xor(acc[c], 32);
    }
    int deg = n1 - n0;
    float s = (deg > 0) ? 1.f / (float)deg : 0.f;
    if (lane < 8) {                       // lane L holds cols L*8..L*8+7
      float* dp = &sh[wslot][r][lane * 8];
#pragma unroll
      for (int c = 0; c < 8; ++c) dp[c] = acc[c] * s;
    }
  }

  // epilogue: all lanes, fully coalesced (wave-private LDS, no barrier)
  float a1 = sh[wslot][0][lane];
  float a2 = sh[wslot][1][lane];
  size_t plane = (size_t)N * 64;
  size_t o = (size_t)v * 64 + lane;
  float t  = out[4 * plane + o];          // h_tar (plane 4 is already final)
  float mm = out[plane + o];              // staged h_mask
  out[o]             = eluf(t + a1);
  out[plane + o]     = eluf(mm + a1);
  out[2 * plane + o] = eluf(t + a2);
  out[3 * plane + o] = eluf(mm + a2);
}

static inline int imin(int a, int b) { return a < b ? a : b; }

extern "C" void kernel_launch(void* const* d_in, const int* in_sizes, int n_in,
                              void* d_out, int out_size, void* d_ws, size_t ws_size,
                              hipStream_t stream) {
  const float* feats0 = (const float*)d_in[0];
  const float* feats1 = (const float*)d_in[1];
  const float* feats2 = (const float*)d_in[2];
  const float* maskf  = (const float*)d_in[3];
  const int* src1 = (const int*)d_in[4];
  const int* dst1 = (const int*)d_in[5];
  const int* src2 = (const int*)d_in[6];
  const int* dst2 = (const int*)d_in[7];
  const float* W0 = (const float*)d_in[8];
  const float* b0 = (const float*)d_in[9];
  const float* W1 = (const float*)d_in[10];
  const float* b1 = (const float*)d_in[11];
  const float* W2 = (const float*)d_in[12];
  const float* b2 = (const float*)d_in[13];
  const float* A0 = (const float*)d_in[14];
  const float* A1 = (const float*)d_in[15];

  int N  = in_sizes[0] / 128;
  int N1 = in_sizes[1] / 128;
  int N2 = in_sizes[2] / 128;
  int E  = in_sizes[4];
  int M  = 2 * N;                    // CSR key space (both relations)

  float* out = (float*)d_out;
  size_t plane = (size_t)N * 64;
  float* h_tar  = out + 4 * plane;   // final value of plane 4 IS h_tar
  float* h_mask = out + plane;       // staged; agg_final overwrites with mask1

  // Workspace (~38 MB; validated ws_size >= ~126 MB).
  // 16B-aligned first: frags (64KB), g1b, g2b (even element counts), row_ptr.
  ushort* frags  = (ushort*)d_ws;              // 32768 ushorts (64 KB)
  ushort* g1b    = frags + 32768;              // N1*64 (7.68MB, 16B-aligned)
  ushort* g2b    = g1b + (size_t)N1 * 64;      // N2*64 (3.84MB)
  int* row_ptr   = (int*)(g2b + (size_t)N2 * 64);  // M+1 (16B-aligned)
  int* btot      = row_ptr + M + 1;            // 256
  int* bstart    = btot + 256;                 // 257
  int* bcur      = bstart + 257;               // 256 (+2 pad)
  int* nbr       = bcur + 258;                 // 2E
  unsigned* pairs = (unsigned*)(nbr + 2 * E);  // 2E

  hipMemsetAsync(btot, 0, 256 * sizeof(int), stream);

  pack_frags_kernel<<<16, 256, 0, stream>>>(W0, W1, W2, A0, A1, frags);

  int t0 = N / 16, t1 = N1 / 16, t2 = N2 / 16;
  lin_elu_kernel<false><<<imin(2048, (t0 + 3) / 4), 256, 0, stream>>>(
      feats0, frags, b0, nullptr, h_tar, t0);
  lin_elu_kernel<false><<<imin(2048, (t0 + 3) / 4), 256, 0, stream>>>(
      maskf, frags, b0, nullptr, h_mask, t0);
  lin_elu_kernel<true><<<imin(2048, (t1 + 3) / 4), 256, 0, stream>>>(
      feats1, frags + 8192, b1, frags + 24576, g1b, t1);
  lin_elu_kernel<true><<<imin(2048, (t2 + 3) / 4), 256, 0, stream>>>(
      feats2, frags + 16384, b2, frags + 28672, g2b, t2);

  // CSR build: bucket-count -> bucket-scan -> partition -> per-bucket sort
  int NB = (M + 1023) >> 10;     // 196 buckets
  bucket_count_kernel<<<512, 256, 0, stream>>>(src1, src2, btot, E, N);
  bscan_kernel<<<1, 256, 0, stream>>>(btot, bstart, bcur, NB);

  int p1blocks = (2 * E + P1_CHUNK - 1) / P1_CHUNK;   // 391 chunks
  partition_kernel<<<p1blocks, 256, 0, stream>>>(
      src1, dst1, src2, dst2, bcur, pairs, E, N);
  scatter_kernel<<<NB, 256, 0, stream>>>(bstart, pairs, row_ptr, nbr, M);

  // Fused gather-mean + epilogue (one wave per node, both relations)
  agg_final_kernel<<<(N + 3) / 4, 256, 0, stream>>>(
      row_ptr, nbr, g1b, g2b, out, N);
}